// Round 6
// baseline (272.703 us; speedup 1.0000x reference)
//
#include <hip/hip_runtime.h>

#define ALPHA 5.0e-4f

typedef short s16x8 __attribute__((ext_vector_type(8)));
typedef unsigned short u16x8 __attribute__((ext_vector_type(8)));
typedef float f32x4 __attribute__((ext_vector_type(4)));

__device__ __forceinline__ unsigned short f2bf(float f) {
    unsigned int u = __builtin_bit_cast(unsigned int, f);
    u += 0x7fffu + ((u >> 16) & 1u);
    return (unsigned short)(u >> 16);
}
__device__ __forceinline__ float bf2f(unsigned short h) {
    return __builtin_bit_cast(float, (unsigned int)h << 16);
}
__device__ __forceinline__ f32x4 mfma16(s16x8 a, s16x8 b, f32x4 c) {
    return __builtin_amdgcn_mfma_f32_16x16x32_bf16(a, b, c, 0, 0, 0);
}

// ---------------------------------------------------------------------------
// Staging helpers -> LDS tile [ROWS][64 bf16], XOR-swizzled (slot ^= row&7).
// ---------------------------------------------------------------------------
template<int ROWS>
__device__ __forceinline__ void stage_kcontig(const float* __restrict__ src, int ld,
                                              unsigned short* __restrict__ lds, int tid)
{
#pragma unroll
    for (int it = 0; it < ROWS * 8 / 256; ++it) {
        const int g = tid + it * 256;
        const int row = g >> 3, s = g & 7;
        const float* p = src + (long long)row * ld + s * 8;
        const float4 x0 = *(const float4*)p;
        const float4 x1 = *(const float4*)(p + 4);
        u16x8 h;
        h[0] = f2bf(x0.x); h[1] = f2bf(x0.y); h[2] = f2bf(x0.z); h[3] = f2bf(x0.w);
        h[4] = f2bf(x1.x); h[5] = f2bf(x1.y); h[6] = f2bf(x1.z); h[7] = f2bf(x1.w);
        *(u16x8*)(lds + row * 64 + ((s ^ (row & 7)) << 3)) = h;
    }
}

template<int ROWS>
__device__ __forceinline__ void stage_kstrided(const float* __restrict__ src, int ld,
                                               unsigned short* __restrict__ lds, int tid)
{
    constexpr int KPT = ROWS * 64 / 256;
    const int m = tid % ROWS, kb = (tid / ROWS) * KPT;
#pragma unroll
    for (int j8 = 0; j8 < KPT / 8; ++j8) {
        u16x8 h;
#pragma unroll
        for (int j = 0; j < 8; ++j)
            h[j] = f2bf(src[(long long)(kb + j8 * 8 + j) * ld + m]);
        const int s = (kb >> 3) + j8;
        *(u16x8*)(lds + m * 64 + ((s ^ (m & 7)) << 3)) = h;
    }
}

template<int ROWS>
__device__ __forceinline__ void stage_kcontig_b(const unsigned short* __restrict__ src, int ld,
                                                unsigned short* __restrict__ lds, int tid)
{
#pragma unroll
    for (int it = 0; it < ROWS * 8 / 256; ++it) {
        const int g = tid + it * 256;
        const int row = g >> 3, s = g & 7;
        const u16x8 h = *(const u16x8*)(src + (long long)row * ld + s * 8);
        *(u16x8*)(lds + row * 64 + ((s ^ (row & 7)) << 3)) = h;
    }
}

template<int ROWS>
__device__ __forceinline__ void stage_kstrided_b(const unsigned short* __restrict__ src, int ld,
                                                 unsigned short* __restrict__ lds, int tid)
{
    constexpr int KPT = ROWS * 64 / 256;
    const int m = tid % ROWS, kb = (tid / ROWS) * KPT;
#pragma unroll
    for (int j8 = 0; j8 < KPT / 8; ++j8) {
        u16x8 h;
#pragma unroll
        for (int j = 0; j < 8; ++j)
            h[j] = src[(long long)(kb + j8 * 8 + j) * ld + m];
        const int s = (kb >> 3) + j8;
        *(u16x8*)(lds + m * 64 + ((s ^ (m & 7)) << 3)) = h;
    }
}

// ---------------------------------------------------------------------------
// Unified MFMA GEMM:  D = alpha*op(A)@op(B) + beta*Cin
//   ABF/BBF: operand is bf16 in global.  OBF: store bf16.
//   OT: store bf16 TRANSPOSED per 256-row batches: D[(row>>8)*sD + col*ldd + (row&255)]
//   CINT: Cin read transposed: Cin[col*sC + row].
// ---------------------------------------------------------------------------
template<int BM, int BN, bool TA, bool TB, bool ABF, bool BBF, bool OBF,
         bool OT = false, bool CINT = false>
__global__ __launch_bounds__(256)
void gemm_mfma(const void* __restrict__ Av, int lda, long long sA,
               const void* __restrict__ Bv, int ldb, long long sB,
               void* __restrict__ Dv, int ldd, long long sD,
               const float* __restrict__ Cin, long long sC,
               float alpha, float beta, int Kd)
{
    constexpr int TWM = BM / 2, TWN = BN / 2;
    constexpr int FM = TWM / 16, FN = TWN / 16;
    __shared__ unsigned short As[BM * 64];
    __shared__ unsigned short Bs[BN * 64];

    const int bx = blockIdx.x, by = blockIdx.y, bz = blockIdx.z;
    const int tid = threadIdx.x;
    const int lane = tid & 63, w = tid >> 6;
    const int wm = w >> 1, wn = w & 1;
    const int lrow = lane & 15, lk = lane >> 4;
    const int m0 = by * BM, n0 = bx * BN;

    f32x4 acc[FM][FN];
#pragma unroll
    for (int i = 0; i < FM; ++i)
#pragma unroll
        for (int j = 0; j < FN; ++j) acc[i][j] = (f32x4){0.f, 0.f, 0.f, 0.f};

    for (int k0 = 0; k0 < Kd; k0 += 64) {
        if (ABF) {
            const unsigned short* Ab = (const unsigned short*)Av + (long long)bz * sA;
            if (!TA) stage_kcontig_b<BM>(Ab + (long long)m0 * lda + k0, lda, As, tid);
            else     stage_kstrided_b<BM>(Ab + (long long)k0 * lda + m0, lda, As, tid);
        } else {
            const float* Ab = (const float*)Av + (long long)bz * sA;
            if (!TA) stage_kcontig<BM>(Ab + (long long)m0 * lda + k0, lda, As, tid);
            else     stage_kstrided<BM>(Ab + (long long)k0 * lda + m0, lda, As, tid);
        }
        if (BBF) {
            const unsigned short* Bb = (const unsigned short*)Bv + (long long)bz * sB;
            if (TB)  stage_kcontig_b<BN>(Bb + (long long)n0 * ldb + k0, ldb, Bs, tid);
            else     stage_kstrided_b<BN>(Bb + (long long)k0 * ldb + n0, ldb, Bs, tid);
        } else {
            const float* Bb = (const float*)Bv + (long long)bz * sB;
            if (TB)  stage_kcontig<BN>(Bb + (long long)n0 * ldb + k0, ldb, Bs, tid);
            else     stage_kstrided<BN>(Bb + (long long)k0 * ldb + n0, ldb, Bs, tid);
        }
        __syncthreads();
#pragma unroll
        for (int kk = 0; kk < 2; ++kk) {
            s16x8 ah[FM], bh[FN];
#pragma unroll
            for (int i = 0; i < FM; ++i) {
                const int row = wm * TWM + i * 16 + lrow;
                const int s = kk * 4 + lk;
                ah[i] = *(const s16x8*)(As + row * 64 + ((s ^ (row & 7)) << 3));
            }
#pragma unroll
            for (int j = 0; j < FN; ++j) {
                const int col = wn * TWN + j * 16 + lrow;
                const int s = kk * 4 + lk;
                bh[j] = *(const s16x8*)(Bs + col * 64 + ((s ^ (col & 7)) << 3));
            }
#pragma unroll
            for (int i = 0; i < FM; ++i)
#pragma unroll
                for (int j = 0; j < FN; ++j)
                    acc[i][j] = mfma16(ah[i], bh[j], acc[i][j]);
        }
        __syncthreads();
    }

#pragma unroll
    for (int i = 0; i < FM; ++i)
#pragma unroll
        for (int j = 0; j < FN; ++j) {
            const int col = n0 + wn * TWN + j * 16 + lrow;
#pragma unroll
            for (int r = 0; r < 4; ++r) {
                const int row = m0 + wm * TWM + i * 16 + lk * 4 + r;
                float v = alpha * acc[i][j][r];
                if (Cin) {
                    const float cv = CINT ? Cin[(long long)col * sC + row]
                                          : Cin[(long long)row * ldd + col];
                    v = fmaf(beta, cv, v);
                }
                if (OT) {
                    ((unsigned short*)Dv)[(long long)(row >> 8) * sD +
                                          (long long)col * ldd + (row & 255)] = f2bf(v);
                } else if (OBF) {
                    ((unsigned short*)Dv + (long long)bz * sD)[(long long)row * ldd + col] = f2bf(v);
                } else {
                    ((float*)Dv + (long long)bz * sD)[(long long)row * ldd + col] = v;
                }
            }
        }
}

// zt_bf16[b][s][c] = bf16(z_seq[s][b][c] + 0.01*noise[s][b][c])
__global__ __launch_bounds__(256)
void prep_zt_kernel(const float* __restrict__ zs, const float* __restrict__ no,
                    unsigned short* __restrict__ ztb)
{
    const long long i8 = (long long)blockIdx.x * 256 + threadIdx.x;
    const long long c8 = i8 & 255;
    const long long bs = i8 >> 8;
    const long long b = bs >> 8, sI = bs & 255;
    const long long in = (sI * 16 + b) * 2048 + c8 * 8;
    const float4 z0 = *(const float4*)(zs + in);
    const float4 z1 = *(const float4*)(zs + in + 4);
    const float4 n0 = *(const float4*)(no + in);
    const float4 n1 = *(const float4*)(no + in + 4);
    u16x8 o;
    o[0] = f2bf(fmaf(0.01f, n0.x, z0.x)); o[1] = f2bf(fmaf(0.01f, n0.y, z0.y));
    o[2] = f2bf(fmaf(0.01f, n0.z, z0.z)); o[3] = f2bf(fmaf(0.01f, n0.w, z0.w));
    o[4] = f2bf(fmaf(0.01f, n1.x, z1.x)); o[5] = f2bf(fmaf(0.01f, n1.y, z1.y));
    o[6] = f2bf(fmaf(0.01f, n1.z, z1.z)); o[7] = f2bf(fmaf(0.01f, n1.w, z1.w));
    *(u16x8*)(ztb + i8 * 8) = o;
}

// ---------------------------------------------------------------------------
// nmm GEMM with fused consumers: nmm[b] = 8a * wT[b] @ zt[b]  (never stored).
// Epilogue computes:
//   uP[bx*2+wn][b][k] : partial u[b,k] = sum_c nmm*zq over this col-group
//   dklpart[block]    : sum (nmm - mm)^2 / prior_var
// ---------------------------------------------------------------------------
__global__ __launch_bounds__(256)
void nmm_fused_kernel(const unsigned short* __restrict__ wTb,
                      const unsigned short* __restrict__ ztb,
                      const float* __restrict__ mm, const float* __restrict__ mlv,
                      const float* __restrict__ zq,
                      float* __restrict__ uP, float* __restrict__ dklpart)
{
    constexpr int BM = 128, BN = 128, TWM = 64, TWN = 64, FM = 4, FN = 4;
    __shared__ unsigned short As[BM * 64];
    __shared__ unsigned short Bs[BN * 64];
    __shared__ float zqs[BN];
    __shared__ float ivars[BM];
    __shared__ float red[256];

    const int bx = blockIdx.x, by = blockIdx.y, bz = blockIdx.z;
    const int tid = threadIdx.x;
    const int lane = tid & 63, w = tid >> 6;
    const int wm = w >> 1, wn = w & 1;
    const int lrow = lane & 15, lk = lane >> 4;
    const int m0 = by * BM, n0 = bx * BN;

    if (tid < 128) zqs[tid] = zq[bz * 2048 + n0 + tid];
    else { const int rr = tid - 128; ivars[rr] = 1.0f / (expf(mlv[m0 + rr]) + 1e-6f); }

    f32x4 acc[FM][FN];
#pragma unroll
    for (int i = 0; i < FM; ++i)
#pragma unroll
        for (int j = 0; j < FN; ++j) acc[i][j] = (f32x4){0.f, 0.f, 0.f, 0.f};

    for (int k0 = 0; k0 < 256; k0 += 64) {
        stage_kcontig_b<BM>(wTb + (long long)bz * 131072 + (long long)m0 * 256 + k0, 256, As, tid);
        stage_kstrided_b<BN>(ztb + (long long)bz * 524288 + (long long)k0 * 2048 + n0, 2048, Bs, tid);
        __syncthreads();
#pragma unroll
        for (int kk = 0; kk < 2; ++kk) {
            s16x8 ah[FM], bh[FN];
#pragma unroll
            for (int i = 0; i < FM; ++i) {
                const int row = wm * TWM + i * 16 + lrow;
                const int s = kk * 4 + lk;
                ah[i] = *(const s16x8*)(As + row * 64 + ((s ^ (row & 7)) << 3));
            }
#pragma unroll
            for (int j = 0; j < FN; ++j) {
                const int col = wn * TWN + j * 16 + lrow;
                const int s = kk * 4 + lk;
                bh[j] = *(const s16x8*)(Bs + col * 64 + ((s ^ (col & 7)) << 3));
            }
#pragma unroll
            for (int i = 0; i < FM; ++i)
#pragma unroll
                for (int j = 0; j < FN; ++j)
                    acc[i][j] = mfma16(ah[i], bh[j], acc[i][j]);
        }
        __syncthreads();
    }

    const float A8 = 8.0f * ALPHA;
    float us[FM][4];
#pragma unroll
    for (int i = 0; i < FM; ++i)
#pragma unroll
        for (int r = 0; r < 4; ++r) us[i][r] = 0.f;
    float da = 0.f;
#pragma unroll
    for (int i = 0; i < FM; ++i)
#pragma unroll
        for (int j = 0; j < FN; ++j) {
            const int cl = wn * TWN + j * 16 + lrow;
#pragma unroll
            for (int r = 0; r < 4; ++r) {
                const int rl = wm * TWM + i * 16 + lk * 4 + r;
                const float v = A8 * acc[i][j][r];
                us[i][r] += v * zqs[cl];
                const float d = v - mm[(long long)(m0 + rl) * 2048 + (n0 + cl)];
                da = fmaf(d * d, ivars[rl], da);
            }
        }
    // reduce u over the 16 lanes (lrow) holding different cols of the same rows
#pragma unroll
    for (int i = 0; i < FM; ++i)
#pragma unroll
        for (int r = 0; r < 4; ++r) {
#pragma unroll
            for (int mask = 1; mask < 16; mask <<= 1)
                us[i][r] += __shfl_xor(us[i][r], mask);
        }
    if (lrow == 0) {
        const int cg = bx * 2 + wn;
#pragma unroll
        for (int i = 0; i < FM; ++i)
#pragma unroll
            for (int r = 0; r < 4; ++r) {
                const int row = m0 + wm * TWM + i * 16 + lk * 4 + r;
                uP[(long long)cg * 8192 + bz * 512 + row] = us[i][r];
            }
    }
    red[tid] = da; __syncthreads();
    for (int st = 128; st > 0; st >>= 1) { if (tid < st) red[tid] += red[tid + st]; __syncthreads(); }
    if (tid == 0) dklpart[bz * 64 + by * 16 + bx] = red[0];
}

// Per-batch: wmean[b] = 8a * sum_cg uP; y[b,s] = sum_k wmean[b,k]*wT[b,k,s]
__global__ __launch_bounds__(512)
void mid_kernel(const float* __restrict__ uP, const unsigned short* __restrict__ wTb,
                float* __restrict__ wmean, float* __restrict__ y)
{
    const int b = blockIdx.x, t = threadIdx.x;
    __shared__ float wmsh[512];
    float s = 0.f;
#pragma unroll 8
    for (int g = 0; g < 32; ++g) s += uP[(long long)g * 8192 + b * 512 + t];
    const float wv = (8.0f * ALPHA) * s;
    wmsh[t] = wv;
    wmean[b * 512 + t] = wv;
    __syncthreads();
    if (t < 256) {
        float yv = 0.f;
        const unsigned short* wp = wTb + (long long)b * 131072 + t;
#pragma unroll 8
        for (int k = 0; k < 512; ++k)
            yv = fmaf(wmsh[k], bf2f(wp[(long long)k * 256]), yv);
        y[b * 256 + t] = yv;
    }
}

// blocks 0..15: zret[b] = 8a * y[b] @ zt[b]; block 16: dkl_M; block 17: dkl_w
__global__ __launch_bounds__(256)
void finalize_kernel(const unsigned short* __restrict__ ztb, const float* __restrict__ y,
                     const float* __restrict__ dklpart, const float* __restrict__ wmean,
                     const float* __restrict__ wlv, float* __restrict__ out)
{
    const int blk = blockIdx.x, t = threadIdx.x;
    if (blk < 16) {
        const int b = blk;
        __shared__ float ys[256];
        ys[t] = y[b * 256 + t];
        __syncthreads();
        const int c0 = t * 8;
        const unsigned short* zp = ztb + (long long)b * 524288 + c0;
        float a[8] = {0.f, 0.f, 0.f, 0.f, 0.f, 0.f, 0.f, 0.f};
        for (int s = 0; s < 256; ++s) {
            const u16x8 zv = *(const u16x8*)(zp + (long long)s * 2048);
            const float yv = ys[s];
#pragma unroll
            for (int jj = 0; jj < 8; ++jj) a[jj] = fmaf(yv, bf2f(zv[jj]), a[jj]);
        }
        const float A8 = 8.0f * ALPHA;
        float* o = out + (long long)b * 2048 + c0;
        *(float4*)o = (float4){A8 * a[0], A8 * a[1], A8 * a[2], A8 * a[3]};
        *(float4*)(o + 4) = (float4){A8 * a[4], A8 * a[5], A8 * a[6], A8 * a[7]};
    } else if (blk == 16) {
        __shared__ float red[256];
        float s = 0.f;
        for (int i = t; i < 1024; i += 256) s += dklpart[i];
        red[t] = s; __syncthreads();
        for (int st = 128; st > 0; st >>= 1) { if (t < st) red[t] += red[t + st]; __syncthreads(); }
        if (t == 0) out[327680] = red[0] * (1.0f / 16.0f);
    } else {
        __shared__ float red[256];
        float s = 0.f;
        for (int i = t; i < 16 * 512; i += 256) { const float v = wmean[i]; s += v * v; }
        red[t] = s; __syncthreads();
        for (int st = 128; st > 0; st >>= 1) { if (t < st) red[t] += red[t + st]; __syncthreads(); }
        if (t == 0) {
            const float l = wlv[0];
            out[327681] = 0.5f * (red[0] + 8192.0f * (expf(l) - 1.0f - l));
        }
    }
}

// Z_r_kv partials: MFMA streaming over W (M=16 b, N=18432 d, K=2048, Ksplit 4)
__global__ __launch_bounds__(256)
void zrkv_mfma_kernel(const float* __restrict__ W, const float* __restrict__ zr,
                      float* __restrict__ part)
{
    const int tid = threadIdx.x, lane = tid & 63, w = tid >> 6;
    const int d0 = blockIdx.x * 64 + w * 16;
    const int kc0 = blockIdx.y * 512;
    const int rr = lane & 15, kq = lane >> 4;
    s16x8 areg[16];
    const float* zb = zr + rr * 2048 + kc0 + kq * 8;
#pragma unroll
    for (int s = 0; s < 16; ++s) {
        const float4 a0 = *(const float4*)(zb + s * 32);
        const float4 a1 = *(const float4*)(zb + s * 32 + 4);
        u16x8 h;
        h[0] = f2bf(a0.x); h[1] = f2bf(a0.y); h[2] = f2bf(a0.z); h[3] = f2bf(a0.w);
        h[4] = f2bf(a1.x); h[5] = f2bf(a1.y); h[6] = f2bf(a1.z); h[7] = f2bf(a1.w);
        areg[s] = __builtin_bit_cast(s16x8, h);
    }
    f32x4 acc = {0.f, 0.f, 0.f, 0.f};
    const float* wb = W + (long long)(d0 + rr) * 2048 + kc0 + kq * 8;
#pragma unroll 4
    for (int s = 0; s < 16; ++s) {
        const float4 b0 = *(const float4*)(wb + s * 32);
        const float4 b1 = *(const float4*)(wb + s * 32 + 4);
        u16x8 h;
        h[0] = f2bf(b0.x); h[1] = f2bf(b0.y); h[2] = f2bf(b0.z); h[3] = f2bf(b0.w);
        h[4] = f2bf(b1.x); h[5] = f2bf(b1.y); h[6] = f2bf(b1.z); h[7] = f2bf(b1.w);
        acc = mfma16(areg[s], __builtin_bit_cast(s16x8, h), acc);
    }
    float* pb = part + ((long long)blockIdx.y * 16 + kq * 4) * 18432 + d0 + rr;
#pragma unroll
    for (int r = 0; r < 4; ++r) pb[(long long)r * 18432] = acc[r];
}

__global__ __launch_bounds__(256)
void zrkv_combine_kernel(const float* __restrict__ part, float* __restrict__ out)
{
    const int idx4 = blockIdx.x * 256 + threadIdx.x;
    const long long base = (long long)idx4 * 4;
    float4 s = {0.f, 0.f, 0.f, 0.f};
#pragma unroll
    for (int g = 0; g < 4; ++g) {
        const float4 v = *(const float4*)(part + (long long)g * 294912 + base);
        s.x += v.x; s.y += v.y; s.z += v.z; s.w += v.w;
    }
    *(float4*)(out + base) = s;
}

extern "C" void kernel_launch(void* const* d_in, const int* in_sizes, int n_in,
                              void* d_out, int out_size, void* d_ws, size_t ws_size,
                              hipStream_t stream)
{
    (void)in_sizes; (void)n_in; (void)out_size; (void)ws_size;
    const float* z_seq   = (const float*)d_in[0];
    const float* z_query = (const float*)d_in[1];
    const float* noise   = (const float*)d_in[2];
    const float* mm      = (const float*)d_in[3];
    const float* mlv     = (const float*)d_in[4];
    const float* wlv     = (const float*)d_in[5];
    const float* WM      = (const float*)d_in[6];
    float* out = (float*)d_out;   // [zr 32768 | Zrkv 294912 | dkl_M | dkl_w]

    char* wsb = (char*)d_ws;
    unsigned short* ztb  = (unsigned short*)(wsb);                  // 16 MB (B,S,C) bf16
    unsigned short* wTb  = (unsigned short*)(wsb + (16LL << 20));   // 4 MB (B,K,S) bf16
    float*          G1   = (float*)(wsb + (24LL << 20));            // 1 MB (K,K) f32
    unsigned short* P1b  = (unsigned short*)(wsb + (26LL << 20));   // 2 MB (C,K) bf16
    float*          uP   = (float*)(wsb + (30LL << 20));            // 1 MB u partials [32][16][512]
    float*          pZ   = (float*)(wsb + (40LL << 20));            // 4.5 MB zrkv partials
    float*          vec  = (float*)(wsb + (48LL << 20));
    float* wmean    = vec;          // 8192
    float* dklpart  = vec + 8192;   // 1024
    float* yvec     = vec + 12288;  // 4096

    // 1. zt (bf16), transposed + noise
    prep_zt_kernel<<<4096, 256, 0, stream>>>(z_seq, noise, ztb);
    // 2. G1 = mm @ mm^T   (512,512,2048)
    gemm_mfma<64,64,false,true,false,false,false><<<dim3(8,8,1),256,0,stream>>>(
        mm,2048,0, mm,2048,0, G1,512,0, nullptr,0, 1.f,0.f, 2048);
    // 3. P1 = 8a*mm^T - 28a^2*(mm^T @ G1) -> bf16  (2048,512,512)
    gemm_mfma<64,64,true,false,false,false,true,false,true><<<dim3(8,32,1),256,0,stream>>>(
        mm,2048,0, G1,512,0, P1b,512,0, mm,2048,
        -28.0f*ALPHA*ALPHA, 8.0f*ALPHA, 512);
    // 4. wT[b][k][s] = (zt @ P1)^T bf16  (4096,512,2048), BN=64 -> 256 blocks
    gemm_mfma<128,64,false,false,true,true,true,true,false><<<dim3(8,32,1),256,0,stream>>>(
        ztb,2048,0, P1b,512,0, wTb,256,131072, nullptr,0, 1.f,0.f, 2048);
    // 5. nmm GEMM with fused u/dkl epilogue (nmm never materialized)
    nmm_fused_kernel<<<dim3(16,4,16),256,0,stream>>>(wTb, ztb, mm, mlv, z_query, uP, dklpart);
    // 6. wmean + y per batch
    mid_kernel<<<16,512,0,stream>>>(uP, wTb, wmean, yvec);
    // 7. z_retrieved + scalars
    finalize_kernel<<<18,256,0,stream>>>(ztb, yvec, dklpart, wmean, wlv, out);
    // 8-9. Z_r_kv = zr @ W^T (K-split MFMA stream + combine)
    zrkv_mfma_kernel<<<dim3(288,4),256,0,stream>>>(WM, out, pZ);
    zrkv_combine_kernel<<<288,256,0,stream>>>(pZ, out + 32768);
}

// Round 7
// 227.694 us; speedup vs baseline: 1.1977x; 1.1977x over previous
//
#include <hip/hip_runtime.h>

#define ALPHA 5.0e-4f

typedef short s16x8 __attribute__((ext_vector_type(8)));
typedef unsigned short u16x8 __attribute__((ext_vector_type(8)));
typedef float f32x4 __attribute__((ext_vector_type(4)));

__device__ __forceinline__ unsigned short f2bf(float f) {
    unsigned int u = __builtin_bit_cast(unsigned int, f);
    u += 0x7fffu + ((u >> 16) & 1u);
    return (unsigned short)(u >> 16);
}
__device__ __forceinline__ float bf2f(unsigned short h) {
    return __builtin_bit_cast(float, (unsigned int)h << 16);
}
__device__ __forceinline__ f32x4 mfma16(s16x8 a, s16x8 b, f32x4 c) {
    return __builtin_amdgcn_mfma_f32_16x16x32_bf16(a, b, c, 0, 0, 0);
}

// ---------------------------------------------------------------------------
// Staging helpers -> LDS tile [ROWS][64 bf16], XOR-swizzled (slot ^= row&7).
// ---------------------------------------------------------------------------
template<int ROWS>
__device__ __forceinline__ void stage_kcontig(const float* __restrict__ src, int ld,
                                              unsigned short* __restrict__ lds, int tid)
{
#pragma unroll
    for (int it = 0; it < ROWS * 8 / 256; ++it) {
        const int g = tid + it * 256;
        const int row = g >> 3, s = g & 7;
        const float* p = src + (long long)row * ld + s * 8;
        const float4 x0 = *(const float4*)p;
        const float4 x1 = *(const float4*)(p + 4);
        u16x8 h;
        h[0] = f2bf(x0.x); h[1] = f2bf(x0.y); h[2] = f2bf(x0.z); h[3] = f2bf(x0.w);
        h[4] = f2bf(x1.x); h[5] = f2bf(x1.y); h[6] = f2bf(x1.z); h[7] = f2bf(x1.w);
        *(u16x8*)(lds + row * 64 + ((s ^ (row & 7)) << 3)) = h;
    }
}

template<int ROWS>
__device__ __forceinline__ void stage_kstrided(const float* __restrict__ src, int ld,
                                               unsigned short* __restrict__ lds, int tid)
{
    constexpr int KPT = ROWS * 64 / 256;
    const int m = tid % ROWS, kb = (tid / ROWS) * KPT;
#pragma unroll
    for (int j8 = 0; j8 < KPT / 8; ++j8) {
        u16x8 h;
#pragma unroll
        for (int j = 0; j < 8; ++j)
            h[j] = f2bf(src[(long long)(kb + j8 * 8 + j) * ld + m]);
        const int s = (kb >> 3) + j8;
        *(u16x8*)(lds + m * 64 + ((s ^ (m & 7)) << 3)) = h;
    }
}

template<int ROWS>
__device__ __forceinline__ void stage_kcontig_b(const unsigned short* __restrict__ src, int ld,
                                                unsigned short* __restrict__ lds, int tid)
{
#pragma unroll
    for (int it = 0; it < ROWS * 8 / 256; ++it) {
        const int g = tid + it * 256;
        const int row = g >> 3, s = g & 7;
        const u16x8 h = *(const u16x8*)(src + (long long)row * ld + s * 8);
        *(u16x8*)(lds + row * 64 + ((s ^ (row & 7)) << 3)) = h;
    }
}

template<int ROWS>
__device__ __forceinline__ void stage_kstrided_b(const unsigned short* __restrict__ src, int ld,
                                                 unsigned short* __restrict__ lds, int tid)
{
    constexpr int KPT = ROWS * 64 / 256;
    const int m = tid % ROWS, kb = (tid / ROWS) * KPT;
#pragma unroll
    for (int j8 = 0; j8 < KPT / 8; ++j8) {
        u16x8 h;
#pragma unroll
        for (int j = 0; j < 8; ++j)
            h[j] = src[(long long)(kb + j8 * 8 + j) * ld + m];
        const int s = (kb >> 3) + j8;
        *(u16x8*)(lds + m * 64 + ((s ^ (m & 7)) << 3)) = h;
    }
}

// ---------------------------------------------------------------------------
// Unified MFMA GEMM:  D = alpha*op(A)@op(B) + beta*Cin
// ---------------------------------------------------------------------------
template<int BM, int BN, bool TA, bool TB, bool ABF, bool BBF, bool OBF,
         bool OT = false, bool CINT = false>
__global__ __launch_bounds__(256)
void gemm_mfma(const void* __restrict__ Av, int lda, long long sA,
               const void* __restrict__ Bv, int ldb, long long sB,
               void* __restrict__ Dv, int ldd, long long sD,
               const float* __restrict__ Cin, long long sC,
               float alpha, float beta, int Kd)
{
    constexpr int TWM = BM / 2, TWN = BN / 2;
    constexpr int FM = TWM / 16, FN = TWN / 16;
    __shared__ unsigned short As[BM * 64];
    __shared__ unsigned short Bs[BN * 64];

    const int bx = blockIdx.x, by = blockIdx.y, bz = blockIdx.z;
    const int tid = threadIdx.x;
    const int lane = tid & 63, w = tid >> 6;
    const int wm = w >> 1, wn = w & 1;
    const int lrow = lane & 15, lk = lane >> 4;
    const int m0 = by * BM, n0 = bx * BN;

    f32x4 acc[FM][FN];
#pragma unroll
    for (int i = 0; i < FM; ++i)
#pragma unroll
        for (int j = 0; j < FN; ++j) acc[i][j] = (f32x4){0.f, 0.f, 0.f, 0.f};

    for (int k0 = 0; k0 < Kd; k0 += 64) {
        if (ABF) {
            const unsigned short* Ab = (const unsigned short*)Av + (long long)bz * sA;
            if (!TA) stage_kcontig_b<BM>(Ab + (long long)m0 * lda + k0, lda, As, tid);
            else     stage_kstrided_b<BM>(Ab + (long long)k0 * lda + m0, lda, As, tid);
        } else {
            const float* Ab = (const float*)Av + (long long)bz * sA;
            if (!TA) stage_kcontig<BM>(Ab + (long long)m0 * lda + k0, lda, As, tid);
            else     stage_kstrided<BM>(Ab + (long long)k0 * lda + m0, lda, As, tid);
        }
        if (BBF) {
            const unsigned short* Bb = (const unsigned short*)Bv + (long long)bz * sB;
            if (TB)  stage_kcontig_b<BN>(Bb + (long long)n0 * ldb + k0, ldb, Bs, tid);
            else     stage_kstrided_b<BN>(Bb + (long long)k0 * ldb + n0, ldb, Bs, tid);
        } else {
            const float* Bb = (const float*)Bv + (long long)bz * sB;
            if (TB)  stage_kcontig<BN>(Bb + (long long)n0 * ldb + k0, ldb, Bs, tid);
            else     stage_kstrided<BN>(Bb + (long long)k0 * ldb + n0, ldb, Bs, tid);
        }
        __syncthreads();
#pragma unroll
        for (int kk = 0; kk < 2; ++kk) {
            s16x8 ah[FM], bh[FN];
#pragma unroll
            for (int i = 0; i < FM; ++i) {
                const int row = wm * TWM + i * 16 + lrow;
                const int s = kk * 4 + lk;
                ah[i] = *(const s16x8*)(As + row * 64 + ((s ^ (row & 7)) << 3));
            }
#pragma unroll
            for (int j = 0; j < FN; ++j) {
                const int col = wn * TWN + j * 16 + lrow;
                const int s = kk * 4 + lk;
                bh[j] = *(const s16x8*)(Bs + col * 64 + ((s ^ (col & 7)) << 3));
            }
#pragma unroll
            for (int i = 0; i < FM; ++i)
#pragma unroll
                for (int j = 0; j < FN; ++j)
                    acc[i][j] = mfma16(ah[i], bh[j], acc[i][j]);
        }
        __syncthreads();
    }

#pragma unroll
    for (int i = 0; i < FM; ++i)
#pragma unroll
        for (int j = 0; j < FN; ++j) {
            const int col = n0 + wn * TWN + j * 16 + lrow;
#pragma unroll
            for (int r = 0; r < 4; ++r) {
                const int row = m0 + wm * TWM + i * 16 + lk * 4 + r;
                float v = alpha * acc[i][j][r];
                if (Cin) {
                    const float cv = CINT ? Cin[(long long)col * sC + row]
                                          : Cin[(long long)row * ldd + col];
                    v = fmaf(beta, cv, v);
                }
                if (OT) {
                    ((unsigned short*)Dv)[(long long)(row >> 8) * sD +
                                          (long long)col * ldd + (row & 255)] = f2bf(v);
                } else if (OBF) {
                    ((unsigned short*)Dv + (long long)bz * sD)[(long long)row * ldd + col] = f2bf(v);
                } else {
                    ((float*)Dv + (long long)bz * sD)[(long long)row * ldd + col] = v;
                }
            }
        }
}

// One block per (b,s) row: zt_bf16 = bf16(z_seq^T + 0.01*noise^T), and
// q[b,s] = <zt_row (fp32), zq[b,:]>  (block reduce).
__global__ __launch_bounds__(256)
void prep_zt_q_kernel(const float* __restrict__ zs, const float* __restrict__ no,
                      const float* __restrict__ zq,
                      unsigned short* __restrict__ ztb, float* __restrict__ q)
{
    const int bs = blockIdx.x;           // b*256 + s
    const int b = bs >> 8, sI = bs & 255;
    const int t = threadIdx.x;
    const long long in = ((long long)sI * 16 + b) * 2048 + t * 8;
    const float4 z0 = *(const float4*)(zs + in);
    const float4 z1 = *(const float4*)(zs + in + 4);
    const float4 n0 = *(const float4*)(no + in);
    const float4 n1 = *(const float4*)(no + in + 4);
    float zf[8];
    zf[0] = fmaf(0.01f, n0.x, z0.x); zf[1] = fmaf(0.01f, n0.y, z0.y);
    zf[2] = fmaf(0.01f, n0.z, z0.z); zf[3] = fmaf(0.01f, n0.w, z0.w);
    zf[4] = fmaf(0.01f, n1.x, z1.x); zf[5] = fmaf(0.01f, n1.y, z1.y);
    zf[6] = fmaf(0.01f, n1.z, z1.z); zf[7] = fmaf(0.01f, n1.w, z1.w);
    u16x8 o;
#pragma unroll
    for (int j = 0; j < 8; ++j) o[j] = f2bf(zf[j]);
    *(u16x8*)(ztb + ((long long)bs * 2048 + t * 8)) = o;
    // q partial
    const float4 q0 = *(const float4*)(zq + b * 2048 + t * 8);
    const float4 q1 = *(const float4*)(zq + b * 2048 + t * 8 + 4);
    float qa = zf[0] * q0.x + zf[1] * q0.y + zf[2] * q0.z + zf[3] * q0.w
             + zf[4] * q1.x + zf[5] * q1.y + zf[6] * q1.z + zf[7] * q1.w;
    __shared__ float red[256];
    red[t] = qa; __syncthreads();
    for (int st = 128; st > 0; st >>= 1) { if (t < st) red[t] += red[t + st]; __syncthreads(); }
    if (t == 0) q[bs] = red[0];
}

// ---------------------------------------------------------------------------
// nmm GEMM with fused dkl: nmm[b] = 8a * wT[b] @ zt[b] (never stored).
// dklpart[block] = sum (nmm - mm)^2 / prior_var  over this tile.
// ---------------------------------------------------------------------------
__global__ __launch_bounds__(256)
void nmm_dkl_kernel(const unsigned short* __restrict__ wTb,
                    const unsigned short* __restrict__ ztb,
                    const float* __restrict__ mm, const float* __restrict__ mlv,
                    float* __restrict__ dklpart)
{
    constexpr int BM = 128, BN = 128, TWM = 64, TWN = 64, FM = 4, FN = 4;
    __shared__ unsigned short As[BM * 64];
    __shared__ unsigned short Bs[BN * 64];
    __shared__ float ivars[BM];
    __shared__ float red[256];

    const int bx = blockIdx.x, by = blockIdx.y, bz = blockIdx.z;
    const int tid = threadIdx.x;
    const int lane = tid & 63, w = tid >> 6;
    const int wm = w >> 1, wn = w & 1;
    const int lrow = lane & 15, lk = lane >> 4;
    const int m0 = by * BM, n0 = bx * BN;

    if (tid < 128) ivars[tid] = 1.0f / (expf(mlv[m0 + tid]) + 1e-6f);

    f32x4 acc[FM][FN];
#pragma unroll
    for (int i = 0; i < FM; ++i)
#pragma unroll
        for (int j = 0; j < FN; ++j) acc[i][j] = (f32x4){0.f, 0.f, 0.f, 0.f};

    for (int k0 = 0; k0 < 256; k0 += 64) {
        stage_kcontig_b<BM>(wTb + (long long)bz * 131072 + (long long)m0 * 256 + k0, 256, As, tid);
        stage_kstrided_b<BN>(ztb + (long long)bz * 524288 + (long long)k0 * 2048 + n0, 2048, Bs, tid);
        __syncthreads();
#pragma unroll
        for (int kk = 0; kk < 2; ++kk) {
            s16x8 ah[FM], bh[FN];
#pragma unroll
            for (int i = 0; i < FM; ++i) {
                const int row = wm * TWM + i * 16 + lrow;
                const int s = kk * 4 + lk;
                ah[i] = *(const s16x8*)(As + row * 64 + ((s ^ (row & 7)) << 3));
            }
#pragma unroll
            for (int j = 0; j < FN; ++j) {
                const int col = wn * TWN + j * 16 + lrow;
                const int s = kk * 4 + lk;
                bh[j] = *(const s16x8*)(Bs + col * 64 + ((s ^ (col & 7)) << 3));
            }
#pragma unroll
            for (int i = 0; i < FM; ++i)
#pragma unroll
                for (int j = 0; j < FN; ++j)
                    acc[i][j] = mfma16(ah[i], bh[j], acc[i][j]);
        }
        __syncthreads();
    }

    const float A8 = 8.0f * ALPHA;
    float da = 0.f;
#pragma unroll
    for (int i = 0; i < FM; ++i)
#pragma unroll
        for (int j = 0; j < FN; ++j) {
            const int cl = wn * TWN + j * 16 + lrow;
#pragma unroll
            for (int r = 0; r < 4; ++r) {
                const int rl = wm * TWM + i * 16 + lk * 4 + r;
                const float v = A8 * acc[i][j][r];
                const float d = v - mm[(long long)(m0 + rl) * 2048 + (n0 + cl)];
                da = fmaf(d * d, ivars[rl], da);
            }
        }
    red[tid] = da; __syncthreads();
    for (int st = 128; st > 0; st >>= 1) { if (tid < st) red[tid] += red[tid + st]; __syncthreads(); }
    if (tid == 0) dklpart[bz * 64 + by * 16 + bx] = red[0];
}

// wmean[b,k] = 64a^2 * sum_s wT[b,k,s]*q[b,s]   grid (32 ktiles, 16 b)
__global__ __launch_bounds__(256)
void u_kernel(const unsigned short* __restrict__ wTb, const float* __restrict__ q,
              float* __restrict__ wmean)
{
    const int b = blockIdx.y, k0 = blockIdx.x * 16;
    const int t = threadIdx.x, row = t >> 4, l = t & 15;
    __shared__ float qs[256];
    if (t < 256) qs[t] = q[b * 256 + t];
    __syncthreads();
    const int k = k0 + row;
    const unsigned short* wp = wTb + (long long)b * 131072 + (long long)k * 256 + l * 16;
    float s = 0.f;
#pragma unroll
    for (int j8 = 0; j8 < 2; ++j8) {
        const u16x8 wv = *(const u16x8*)(wp + j8 * 8);
#pragma unroll
        for (int jj = 0; jj < 8; ++jj)
            s = fmaf(bf2f(wv[jj]), qs[l * 16 + j8 * 8 + jj], s);
    }
    for (int off = 8; off; off >>= 1) s += __shfl_down(s, off, 16);
    if (l == 0) wmean[b * 512 + k] = (64.0f * ALPHA * ALPHA) * s;
}

// yP[kt][b][s] = sum_{k in kt*64..} wmean[b,k]*wT[b,k,s]   grid (8 ktiles, 16 b)
__global__ __launch_bounds__(256)
void y_kernel(const unsigned short* __restrict__ wTb, const float* __restrict__ wmean,
              float* __restrict__ yP)
{
    const int kt = blockIdx.x, b = blockIdx.y, t = threadIdx.x;
    __shared__ float wms[64];
    if (t < 64) wms[t] = wmean[b * 512 + kt * 64 + t];
    __syncthreads();
    const unsigned short* wp = wTb + (long long)b * 131072 + (long long)(kt * 64) * 256 + t;
    float s = 0.f;
#pragma unroll 8
    for (int k = 0; k < 64; ++k)
        s = fmaf(wms[k], bf2f(wp[(long long)k * 256]), s);
    yP[((long long)kt * 16 + b) * 256 + t] = s;
}

// blocks 0..255: zr[b, ct*128 + c] = 8a * sum_s y[b,s]*zt[b,s,c]
// block 256: dkl_M; block 257: dkl_w
__global__ __launch_bounds__(256)
void zret_fin_kernel(const unsigned short* __restrict__ ztb, const float* __restrict__ yP,
                     const float* __restrict__ dklpart, const float* __restrict__ wmean,
                     const float* __restrict__ wlv, float* __restrict__ out)
{
    const int blk = blockIdx.x, t = threadIdx.x;
    if (blk < 256) {
        const int b = blk & 15, ct = blk >> 4;
        __shared__ float ys[256];
        __shared__ float red2[256];
        {
            float s = 0.f;
#pragma unroll
            for (int kt = 0; kt < 8; ++kt) s += yP[((long long)kt * 16 + b) * 256 + t];
            ys[t] = s;
        }
        __syncthreads();
        const int c = ct * 128 + (t & 127), sh = t >> 7;
        const unsigned short* zp = ztb + (long long)b * 524288 + c;
        float acc = 0.f;
        const int sbase = sh * 128;
#pragma unroll 8
        for (int s = 0; s < 128; ++s)
            acc = fmaf(ys[sbase + s], bf2f(zp[(long long)(sbase + s) * 2048]), acc);
        red2[t] = acc; __syncthreads();
        if (sh == 0)
            out[(long long)b * 2048 + c] = (8.0f * ALPHA) * (red2[t] + red2[t + 128]);
    } else if (blk == 256) {
        __shared__ float red[256];
        float s = 0.f;
        for (int i = t; i < 1024; i += 256) s += dklpart[i];
        red[t] = s; __syncthreads();
        for (int st = 128; st > 0; st >>= 1) { if (t < st) red[t] += red[t + st]; __syncthreads(); }
        if (t == 0) out[327680] = red[0] * (1.0f / 16.0f);
    } else {
        __shared__ float red[256];
        float s = 0.f;
        for (int i = t; i < 16 * 512; i += 256) { const float v = wmean[i]; s += v * v; }
        red[t] = s; __syncthreads();
        for (int st = 128; st > 0; st >>= 1) { if (t < st) red[t] += red[t + st]; __syncthreads(); }
        if (t == 0) {
            const float l = wlv[0];
            out[327681] = 0.5f * (red[0] + 8192.0f * (expf(l) - 1.0f - l));
        }
    }
}

// Z_r_kv partials: MFMA streaming over W (M=16 b, N=18432 d, K=2048, Ksplit 4)
__global__ __launch_bounds__(256)
void zrkv_mfma_kernel(const float* __restrict__ W, const float* __restrict__ zr,
                      float* __restrict__ part)
{
    const int tid = threadIdx.x, lane = tid & 63, w = tid >> 6;
    const int d0 = blockIdx.x * 64 + w * 16;
    const int kc0 = blockIdx.y * 512;
    const int rr = lane & 15, kq = lane >> 4;
    s16x8 areg[16];
    const float* zb = zr + rr * 2048 + kc0 + kq * 8;
#pragma unroll
    for (int s = 0; s < 16; ++s) {
        const float4 a0 = *(const float4*)(zb + s * 32);
        const float4 a1 = *(const float4*)(zb + s * 32 + 4);
        u16x8 h;
        h[0] = f2bf(a0.x); h[1] = f2bf(a0.y); h[2] = f2bf(a0.z); h[3] = f2bf(a0.w);
        h[4] = f2bf(a1.x); h[5] = f2bf(a1.y); h[6] = f2bf(a1.z); h[7] = f2bf(a1.w);
        areg[s] = __builtin_bit_cast(s16x8, h);
    }
    f32x4 acc = {0.f, 0.f, 0.f, 0.f};
    const float* wb = W + (long long)(d0 + rr) * 2048 + kc0 + kq * 8;
#pragma unroll 4
    for (int s = 0; s < 16; ++s) {
        const float4 b0 = *(const float4*)(wb + s * 32);
        const float4 b1 = *(const float4*)(wb + s * 32 + 4);
        u16x8 h;
        h[0] = f2bf(b0.x); h[1] = f2bf(b0.y); h[2] = f2bf(b0.z); h[3] = f2bf(b0.w);
        h[4] = f2bf(b1.x); h[5] = f2bf(b1.y); h[6] = f2bf(b1.z); h[7] = f2bf(b1.w);
        acc = mfma16(areg[s], __builtin_bit_cast(s16x8, h), acc);
    }
    float* pb = part + ((long long)blockIdx.y * 16 + kq * 4) * 18432 + d0 + rr;
#pragma unroll
    for (int r = 0; r < 4; ++r) pb[(long long)r * 18432] = acc[r];
}

__global__ __launch_bounds__(256)
void zrkv_combine_kernel(const float* __restrict__ part, float* __restrict__ out)
{
    const int idx4 = blockIdx.x * 256 + threadIdx.x;
    const long long base = (long long)idx4 * 4;
    float4 s = {0.f, 0.f, 0.f, 0.f};
#pragma unroll
    for (int g = 0; g < 4; ++g) {
        const float4 v = *(const float4*)(part + (long long)g * 294912 + base);
        s.x += v.x; s.y += v.y; s.z += v.z; s.w += v.w;
    }
    *(float4*)(out + base) = s;
}

extern "C" void kernel_launch(void* const* d_in, const int* in_sizes, int n_in,
                              void* d_out, int out_size, void* d_ws, size_t ws_size,
                              hipStream_t stream)
{
    (void)in_sizes; (void)n_in; (void)out_size; (void)ws_size;
    const float* z_seq   = (const float*)d_in[0];
    const float* z_query = (const float*)d_in[1];
    const float* noise   = (const float*)d_in[2];
    const float* mm      = (const float*)d_in[3];
    const float* mlv     = (const float*)d_in[4];
    const float* wlv     = (const float*)d_in[5];
    const float* WM      = (const float*)d_in[6];
    float* out = (float*)d_out;   // [zr 32768 | Zrkv 294912 | dkl_M | dkl_w]

    char* wsb = (char*)d_ws;
    unsigned short* ztb  = (unsigned short*)(wsb);                  // 16 MB (B,S,C) bf16
    unsigned short* wTb  = (unsigned short*)(wsb + (16LL << 20));   // 4 MB (B,K,S) bf16
    float*          G1   = (float*)(wsb + (24LL << 20));            // 1 MB (K,K) f32
    unsigned short* P1b  = (unsigned short*)(wsb + (26LL << 20));   // 2 MB (C,K) bf16
    float*          pZ   = (float*)(wsb + (40LL << 20));            // 4.5 MB zrkv partials
    float*          vec  = (float*)(wsb + (48LL << 20));
    float* qvec     = vec;           // 4096
    float* wmean    = vec + 4096;    // 8192
    float* dklpart  = vec + 12288;   // 1024
    float* yP       = vec + 16384;   // 32768 [8][16][256]

    // 1. zt (bf16) + q = zt @ zq fused
    prep_zt_q_kernel<<<4096, 256, 0, stream>>>(z_seq, noise, z_query, ztb, qvec);
    // 2. G1 = mm @ mm^T   (512,512,2048)
    gemm_mfma<64,64,false,true,false,false,false><<<dim3(8,8,1),256,0,stream>>>(
        mm,2048,0, mm,2048,0, G1,512,0, nullptr,0, 1.f,0.f, 2048);
    // 3. P1 = 8a*mm^T - 28a^2*(mm^T @ G1) -> bf16  (2048,512,512)
    gemm_mfma<64,64,true,false,false,false,true,false,true><<<dim3(8,32,1),256,0,stream>>>(
        mm,2048,0, G1,512,0, P1b,512,0, mm,2048,
        -28.0f*ALPHA*ALPHA, 8.0f*ALPHA, 512);
    // 4. wT[b][k][s] = (zt @ P1)^T bf16  (4096,512,2048)
    gemm_mfma<128,64,false,false,true,true,true,true,false><<<dim3(8,32,1),256,0,stream>>>(
        ztb,2048,0, P1b,512,0, wTb,256,131072, nullptr,0, 1.f,0.f, 2048);
    // 5. nmm GEMM with fused dkl (nmm never materialized)
    nmm_dkl_kernel<<<dim3(16,4,16),256,0,stream>>>(wTb, ztb, mm, mlv, dklpart);
    // 6. wmean = 64a^2 * wT @ q
    u_kernel<<<dim3(32,16),256,0,stream>>>(wTb, qvec, wmean);
    // 7. y partials = wmean @ wT
    y_kernel<<<dim3(8,16),256,0,stream>>>(wTb, wmean, yP);
    // 8. z_retrieved = 8a * y @ zt, + dkl_M + dkl_w
    zret_fin_kernel<<<258,256,0,stream>>>(ztb, yP, dklpart, wmean, wlv, out);
    // 9-10. Z_r_kv = zr @ W^T (K-split MFMA stream + combine)
    zrkv_mfma_kernel<<<dim3(288,4),256,0,stream>>>(WM, out, pZ);
    zrkv_combine_kernel<<<288,256,0,stream>>>(pZ, out + 32768);
}

// Round 8
// 202.989 us; speedup vs baseline: 1.3434x; 1.1217x over previous
//
#include <hip/hip_runtime.h>

#define ALPHA 5.0e-4f

typedef short s16x8 __attribute__((ext_vector_type(8)));
typedef unsigned short u16x8 __attribute__((ext_vector_type(8)));
typedef float f32x4 __attribute__((ext_vector_type(4)));

__device__ __forceinline__ unsigned short f2bf(float f) {
    unsigned int u = __builtin_bit_cast(unsigned int, f);
    u += 0x7fffu + ((u >> 16) & 1u);
    return (unsigned short)(u >> 16);
}
__device__ __forceinline__ float bf2f(unsigned short h) {
    return __builtin_bit_cast(float, (unsigned int)h << 16);
}
__device__ __forceinline__ f32x4 mfma16(s16x8 a, s16x8 b, f32x4 c) {
    return __builtin_amdgcn_mfma_f32_16x16x32_bf16(a, b, c, 0, 0, 0);
}

// ---------------------------------------------------------------------------
// Staging helpers -> LDS tile [ROWS][64 bf16], XOR-swizzled (slot ^= row&7).
// ---------------------------------------------------------------------------
template<int ROWS>
__device__ __forceinline__ void stage_kcontig(const float* __restrict__ src, int ld,
                                              unsigned short* __restrict__ lds, int tid)
{
#pragma unroll
    for (int it = 0; it < ROWS * 8 / 256; ++it) {
        const int g = tid + it * 256;
        const int row = g >> 3, s = g & 7;
        const float* p = src + (long long)row * ld + s * 8;
        const float4 x0 = *(const float4*)p;
        const float4 x1 = *(const float4*)(p + 4);
        u16x8 h;
        h[0] = f2bf(x0.x); h[1] = f2bf(x0.y); h[2] = f2bf(x0.z); h[3] = f2bf(x0.w);
        h[4] = f2bf(x1.x); h[5] = f2bf(x1.y); h[6] = f2bf(x1.z); h[7] = f2bf(x1.w);
        *(u16x8*)(lds + row * 64 + ((s ^ (row & 7)) << 3)) = h;
    }
}

template<int ROWS>
__device__ __forceinline__ void stage_kstrided(const float* __restrict__ src, int ld,
                                               unsigned short* __restrict__ lds, int tid)
{
    constexpr int KPT = ROWS * 64 / 256;
    const int m = tid % ROWS, kb = (tid / ROWS) * KPT;
#pragma unroll
    for (int j8 = 0; j8 < KPT / 8; ++j8) {
        u16x8 h;
#pragma unroll
        for (int j = 0; j < 8; ++j)
            h[j] = f2bf(src[(long long)(kb + j8 * 8 + j) * ld + m]);
        const int s = (kb >> 3) + j8;
        *(u16x8*)(lds + m * 64 + ((s ^ (m & 7)) << 3)) = h;
    }
}

template<int ROWS>
__device__ __forceinline__ void stage_kcontig_b(const unsigned short* __restrict__ src, int ld,
                                                unsigned short* __restrict__ lds, int tid)
{
#pragma unroll
    for (int it = 0; it < ROWS * 8 / 256; ++it) {
        const int g = tid + it * 256;
        const int row = g >> 3, s = g & 7;
        const u16x8 h = *(const u16x8*)(src + (long long)row * ld + s * 8);
        *(u16x8*)(lds + row * 64 + ((s ^ (row & 7)) << 3)) = h;
    }
}

template<int ROWS>
__device__ __forceinline__ void stage_kstrided_b(const unsigned short* __restrict__ src, int ld,
                                                 unsigned short* __restrict__ lds, int tid)
{
    constexpr int KPT = ROWS * 64 / 256;
    const int m = tid % ROWS, kb = (tid / ROWS) * KPT;
#pragma unroll
    for (int j8 = 0; j8 < KPT / 8; ++j8) {
        u16x8 h;
#pragma unroll
        for (int j = 0; j < 8; ++j)
            h[j] = src[(long long)(kb + j8 * 8 + j) * ld + m];
        const int s = (kb >> 3) + j8;
        *(u16x8*)(lds + m * 64 + ((s ^ (m & 7)) << 3)) = h;
    }
}

// ---------------------------------------------------------------------------
// Unified MFMA GEMM:  D = alpha*op(A)@op(B) + beta*Cin
// ---------------------------------------------------------------------------
template<int BM, int BN, bool TA, bool TB, bool ABF, bool BBF, bool OBF,
         bool OT = false, bool CINT = false>
__global__ __launch_bounds__(256)
void gemm_mfma(const void* __restrict__ Av, int lda, long long sA,
               const void* __restrict__ Bv, int ldb, long long sB,
               void* __restrict__ Dv, int ldd, long long sD,
               const float* __restrict__ Cin, long long sC,
               float alpha, float beta, int Kd)
{
    constexpr int TWM = BM / 2, TWN = BN / 2;
    constexpr int FM = TWM / 16, FN = TWN / 16;
    __shared__ unsigned short As[BM * 64];
    __shared__ unsigned short Bs[BN * 64];

    const int bx = blockIdx.x, by = blockIdx.y, bz = blockIdx.z;
    const int tid = threadIdx.x;
    const int lane = tid & 63, w = tid >> 6;
    const int wm = w >> 1, wn = w & 1;
    const int lrow = lane & 15, lk = lane >> 4;
    const int m0 = by * BM, n0 = bx * BN;

    f32x4 acc[FM][FN];
#pragma unroll
    for (int i = 0; i < FM; ++i)
#pragma unroll
        for (int j = 0; j < FN; ++j) acc[i][j] = (f32x4){0.f, 0.f, 0.f, 0.f};

    for (int k0 = 0; k0 < Kd; k0 += 64) {
        if (ABF) {
            const unsigned short* Ab = (const unsigned short*)Av + (long long)bz * sA;
            if (!TA) stage_kcontig_b<BM>(Ab + (long long)m0 * lda + k0, lda, As, tid);
            else     stage_kstrided_b<BM>(Ab + (long long)k0 * lda + m0, lda, As, tid);
        } else {
            const float* Ab = (const float*)Av + (long long)bz * sA;
            if (!TA) stage_kcontig<BM>(Ab + (long long)m0 * lda + k0, lda, As, tid);
            else     stage_kstrided<BM>(Ab + (long long)k0 * lda + m0, lda, As, tid);
        }
        if (BBF) {
            const unsigned short* Bb = (const unsigned short*)Bv + (long long)bz * sB;
            if (TB)  stage_kcontig_b<BN>(Bb + (long long)n0 * ldb + k0, ldb, Bs, tid);
            else     stage_kstrided_b<BN>(Bb + (long long)k0 * ldb + n0, ldb, Bs, tid);
        } else {
            const float* Bb = (const float*)Bv + (long long)bz * sB;
            if (TB)  stage_kcontig<BN>(Bb + (long long)n0 * ldb + k0, ldb, Bs, tid);
            else     stage_kstrided<BN>(Bb + (long long)k0 * ldb + n0, ldb, Bs, tid);
        }
        __syncthreads();
#pragma unroll
        for (int kk = 0; kk < 2; ++kk) {
            s16x8 ah[FM], bh[FN];
#pragma unroll
            for (int i = 0; i < FM; ++i) {
                const int row = wm * TWM + i * 16 + lrow;
                const int s = kk * 4 + lk;
                ah[i] = *(const s16x8*)(As + row * 64 + ((s ^ (row & 7)) << 3));
            }
#pragma unroll
            for (int j = 0; j < FN; ++j) {
                const int col = wn * TWN + j * 16 + lrow;
                const int s = kk * 4 + lk;
                bh[j] = *(const s16x8*)(Bs + col * 64 + ((s ^ (col & 7)) << 3));
            }
#pragma unroll
            for (int i = 0; i < FM; ++i)
#pragma unroll
                for (int j = 0; j < FN; ++j)
                    acc[i][j] = mfma16(ah[i], bh[j], acc[i][j]);
        }
        __syncthreads();
    }

#pragma unroll
    for (int i = 0; i < FM; ++i)
#pragma unroll
        for (int j = 0; j < FN; ++j) {
            const int col = n0 + wn * TWN + j * 16 + lrow;
#pragma unroll
            for (int r = 0; r < 4; ++r) {
                const int row = m0 + wm * TWM + i * 16 + lk * 4 + r;
                float v = alpha * acc[i][j][r];
                if (Cin) {
                    const float cv = CINT ? Cin[(long long)col * sC + row]
                                          : Cin[(long long)row * ldd + col];
                    v = fmaf(beta, cv, v);
                }
                if (OT) {
                    ((unsigned short*)Dv)[(long long)(row >> 8) * sD +
                                          (long long)col * ldd + (row & 255)] = f2bf(v);
                } else if (OBF) {
                    ((unsigned short*)Dv + (long long)bz * sD)[(long long)row * ldd + col] = f2bf(v);
                } else {
                    ((float*)Dv + (long long)bz * sD)[(long long)row * ldd + col] = v;
                }
            }
        }
}

// One block per (b,s) row: zt_bf16 = bf16(z_seq^T + 0.01*noise^T), and
// q[b,s] = <zt_row (fp32), zq[b,:]>. z_seq/noise loads are non-temporal
// (streamed once; keep L2 for ztb and downstream).
__global__ __launch_bounds__(256)
void prep_zt_q_kernel(const float* __restrict__ zs, const float* __restrict__ no,
                      const float* __restrict__ zq,
                      unsigned short* __restrict__ ztb, float* __restrict__ q)
{
    const int bs = blockIdx.x;           // b*256 + s
    const int b = bs >> 8, sI = bs & 255;
    const int t = threadIdx.x;
    const long long in = ((long long)sI * 16 + b) * 2048 + t * 8;
    const f32x4 z0 = __builtin_nontemporal_load((const f32x4*)(zs + in));
    const f32x4 z1 = __builtin_nontemporal_load((const f32x4*)(zs + in + 4));
    const f32x4 n0 = __builtin_nontemporal_load((const f32x4*)(no + in));
    const f32x4 n1 = __builtin_nontemporal_load((const f32x4*)(no + in + 4));
    float zf[8];
#pragma unroll
    for (int j = 0; j < 4; ++j) {
        zf[j]     = fmaf(0.01f, n0[j], z0[j]);
        zf[j + 4] = fmaf(0.01f, n1[j], z1[j]);
    }
    u16x8 o;
#pragma unroll
    for (int j = 0; j < 8; ++j) o[j] = f2bf(zf[j]);
    *(u16x8*)(ztb + ((long long)bs * 2048 + t * 8)) = o;
    const float4 q0 = *(const float4*)(zq + b * 2048 + t * 8);
    const float4 q1 = *(const float4*)(zq + b * 2048 + t * 8 + 4);
    float qa = zf[0] * q0.x + zf[1] * q0.y + zf[2] * q0.z + zf[3] * q0.w
             + zf[4] * q1.x + zf[5] * q1.y + zf[6] * q1.z + zf[7] * q1.w;
    __shared__ float red[256];
    red[t] = qa; __syncthreads();
    for (int st = 128; st > 0; st >>= 1) { if (t < st) red[t] += red[t + st]; __syncthreads(); }
    if (t == 0) q[bs] = red[0];
}

// ---------------------------------------------------------------------------
// nmm GEMM with fused dkl: nmm[b] = 8a * wT[b] @ zt[b] (never stored).
// ---------------------------------------------------------------------------
__global__ __launch_bounds__(256)
void nmm_dkl_kernel(const unsigned short* __restrict__ wTb,
                    const unsigned short* __restrict__ ztb,
                    const float* __restrict__ mm, const float* __restrict__ mlv,
                    float* __restrict__ dklpart)
{
    constexpr int BM = 128, BN = 128, TWM = 64, TWN = 64, FM = 4, FN = 4;
    __shared__ unsigned short As[BM * 64];
    __shared__ unsigned short Bs[BN * 64];
    __shared__ float ivars[BM];
    __shared__ float red[256];

    const int bx = blockIdx.x, by = blockIdx.y, bz = blockIdx.z;
    const int tid = threadIdx.x;
    const int lane = tid & 63, w = tid >> 6;
    const int wm = w >> 1, wn = w & 1;
    const int lrow = lane & 15, lk = lane >> 4;
    const int m0 = by * BM, n0 = bx * BN;

    if (tid < 128) ivars[tid] = 1.0f / (expf(mlv[m0 + tid]) + 1e-6f);

    f32x4 acc[FM][FN];
#pragma unroll
    for (int i = 0; i < FM; ++i)
#pragma unroll
        for (int j = 0; j < FN; ++j) acc[i][j] = (f32x4){0.f, 0.f, 0.f, 0.f};

    for (int k0 = 0; k0 < 256; k0 += 64) {
        stage_kcontig_b<BM>(wTb + (long long)bz * 131072 + (long long)m0 * 256 + k0, 256, As, tid);
        stage_kstrided_b<BN>(ztb + (long long)bz * 524288 + (long long)k0 * 2048 + n0, 2048, Bs, tid);
        __syncthreads();
#pragma unroll
        for (int kk = 0; kk < 2; ++kk) {
            s16x8 ah[FM], bh[FN];
#pragma unroll
            for (int i = 0; i < FM; ++i) {
                const int row = wm * TWM + i * 16 + lrow;
                const int s = kk * 4 + lk;
                ah[i] = *(const s16x8*)(As + row * 64 + ((s ^ (row & 7)) << 3));
            }
#pragma unroll
            for (int j = 0; j < FN; ++j) {
                const int col = wn * TWN + j * 16 + lrow;
                const int s = kk * 4 + lk;
                bh[j] = *(const s16x8*)(Bs + col * 64 + ((s ^ (col & 7)) << 3));
            }
#pragma unroll
            for (int i = 0; i < FM; ++i)
#pragma unroll
                for (int j = 0; j < FN; ++j)
                    acc[i][j] = mfma16(ah[i], bh[j], acc[i][j]);
        }
        __syncthreads();
    }

    const float A8 = 8.0f * ALPHA;
    float da = 0.f;
#pragma unroll
    for (int i = 0; i < FM; ++i)
#pragma unroll
        for (int j = 0; j < FN; ++j) {
            const int cl = wn * TWN + j * 16 + lrow;
#pragma unroll
            for (int r = 0; r < 4; ++r) {
                const int rl = wm * TWM + i * 16 + lk * 4 + r;
                const float v = A8 * acc[i][j][r];
                const float d = v - mm[(long long)(m0 + rl) * 2048 + (n0 + cl)];
                da = fmaf(d * d, ivars[rl], da);
            }
        }
    red[tid] = da; __syncthreads();
    for (int st = 128; st > 0; st >>= 1) { if (tid < st) red[tid] += red[tid + st]; __syncthreads(); }
    if (tid == 0) dklpart[bz * 64 + by * 16 + bx] = red[0];
}

// wmean[b,k] = 64a^2 * sum_s wT[b,k,s]*q[b,s]   grid (32 ktiles, 16 b)
__global__ __launch_bounds__(256)
void u_kernel(const unsigned short* __restrict__ wTb, const float* __restrict__ q,
              float* __restrict__ wmean)
{
    const int b = blockIdx.y, k0 = blockIdx.x * 16;
    const int t = threadIdx.x, row = t >> 4, l = t & 15;
    __shared__ float qs[256];
    if (t < 256) qs[t] = q[b * 256 + t];
    __syncthreads();
    const int k = k0 + row;
    const unsigned short* wp = wTb + (long long)b * 131072 + (long long)k * 256 + l * 16;
    float s = 0.f;
#pragma unroll
    for (int j8 = 0; j8 < 2; ++j8) {
        const u16x8 wv = *(const u16x8*)(wp + j8 * 8);
#pragma unroll
        for (int jj = 0; jj < 8; ++jj)
            s = fmaf(bf2f(wv[jj]), qs[l * 16 + j8 * 8 + jj], s);
    }
    for (int off = 8; off; off >>= 1) s += __shfl_down(s, off, 16);
    if (l == 0) wmean[b * 512 + k] = (64.0f * ALPHA * ALPHA) * s;
}

// yP[kt][b][s] = sum_{k in kt*64..} wmean[b,k]*wT[b,k,s]   grid (8 ktiles, 16 b)
__global__ __launch_bounds__(256)
void y_kernel(const unsigned short* __restrict__ wTb, const float* __restrict__ wmean,
              float* __restrict__ yP)
{
    const int kt = blockIdx.x, b = blockIdx.y, t = threadIdx.x;
    __shared__ float wms[64];
    if (t < 64) wms[t] = wmean[b * 512 + kt * 64 + t];
    __syncthreads();
    const unsigned short* wp = wTb + (long long)b * 131072 + (long long)(kt * 64) * 256 + t;
    float s = 0.f;
#pragma unroll 8
    for (int k = 0; k < 64; ++k)
        s = fmaf(wms[k], bf2f(wp[(long long)k * 256]), s);
    yP[((long long)kt * 16 + b) * 256 + t] = s;
}

// blocks 0..255: zr[b, ct*128 + c]; block 256: dkl_M; block 257: dkl_w
__global__ __launch_bounds__(256)
void zret_fin_kernel(const unsigned short* __restrict__ ztb, const float* __restrict__ yP,
                     const float* __restrict__ dklpart, const float* __restrict__ wmean,
                     const float* __restrict__ wlv, float* __restrict__ out)
{
    const int blk = blockIdx.x, t = threadIdx.x;
    if (blk < 256) {
        const int b = blk & 15, ct = blk >> 4;
        __shared__ float ys[256];
        __shared__ float red2[256];
        {
            float s = 0.f;
#pragma unroll
            for (int kt = 0; kt < 8; ++kt) s += yP[((long long)kt * 16 + b) * 256 + t];
            ys[t] = s;
        }
        __syncthreads();
        const int c = ct * 128 + (t & 127), sh = t >> 7;
        const unsigned short* zp = ztb + (long long)b * 524288 + c;
        float acc = 0.f;
        const int sbase = sh * 128;
#pragma unroll 8
        for (int s = 0; s < 128; ++s)
            acc = fmaf(ys[sbase + s], bf2f(zp[(long long)(sbase + s) * 2048]), acc);
        red2[t] = acc; __syncthreads();
        if (sh == 0)
            out[(long long)b * 2048 + c] = (8.0f * ALPHA) * (red2[t] + red2[t + 128]);
    } else if (blk == 256) {
        __shared__ float red[256];
        float s = 0.f;
        for (int i = t; i < 1024; i += 256) s += dklpart[i];
        red[t] = s; __syncthreads();
        for (int st = 128; st > 0; st >>= 1) { if (t < st) red[t] += red[t + st]; __syncthreads(); }
        if (t == 0) out[327680] = red[0] * (1.0f / 16.0f);
    } else {
        __shared__ float red[256];
        float s = 0.f;
        for (int i = t; i < 16 * 512; i += 256) { const float v = wmean[i]; s += v * v; }
        red[t] = s; __syncthreads();
        for (int st = 128; st > 0; st >>= 1) { if (t < st) red[t] += red[t + st]; __syncthreads(); }
        if (t == 0) {
            const float l = wlv[0];
            out[327681] = 0.5f * (red[0] + 8192.0f * (expf(l) - 1.0f - l));
        }
    }
}

// ---------------------------------------------------------------------------
// Z_r_kv partials: M=16 b, N=18432 d, K=2048, K-split 8 -> grid (288, 8).
// W loads are NON-TEMPORAL (zero reuse; don't evict dirty workspace).
// Store layout: part[((ky*288+bx)*4+w)*256 + (kq*4+r)*16 + rr]  (64B runs).
// ---------------------------------------------------------------------------
__global__ __launch_bounds__(256)
void zrkv_mfma_kernel(const float* __restrict__ W, const float* __restrict__ zr,
                      float* __restrict__ part)
{
    const int tid = threadIdx.x, lane = tid & 63, w = tid >> 6;
    const int bx = blockIdx.x, ky = blockIdx.y;
    const int d0 = bx * 64 + w * 16;
    const int kc0 = ky * 256;
    const int rr = lane & 15, kq = lane >> 4;
    // A-frags (zr rows = b): 8 K-steps of 32
    s16x8 areg[8];
    const float* zb = zr + rr * 2048 + kc0 + kq * 8;
#pragma unroll
    for (int s = 0; s < 8; ++s) {
        const f32x4 a0 = *(const f32x4*)(zb + s * 32);
        const f32x4 a1 = *(const f32x4*)(zb + s * 32 + 4);
        u16x8 h;
#pragma unroll
        for (int j = 0; j < 4; ++j) { h[j] = f2bf(a0[j]); h[j + 4] = f2bf(a1[j]); }
        areg[s] = __builtin_bit_cast(s16x8, h);
    }
    f32x4 acc = {0.f, 0.f, 0.f, 0.f};
    const float* wb = W + (long long)(d0 + rr) * 2048 + kc0 + kq * 8;
#pragma unroll
    for (int s = 0; s < 8; ++s) {
        const f32x4 b0 = __builtin_nontemporal_load((const f32x4*)(wb + s * 32));
        const f32x4 b1 = __builtin_nontemporal_load((const f32x4*)(wb + s * 32 + 4));
        u16x8 h;
#pragma unroll
        for (int j = 0; j < 4; ++j) { h[j] = f2bf(b0[j]); h[j + 4] = f2bf(b1[j]); }
        acc = mfma16(areg[s], __builtin_bit_cast(s16x8, h), acc);
    }
    float* pb = part + (((long long)ky * 288 + bx) * 4 + w) * 256 + kq * 64 + rr;
#pragma unroll
    for (int r = 0; r < 4; ++r) pb[r * 16] = acc[r];
}

// out[b*18432+d] = sum_ky part[...]   grid (72, 16)
__global__ __launch_bounds__(256)
void zrkv_combine_kernel(const float* __restrict__ part, float* __restrict__ out)
{
    const int b = blockIdx.y;
    const int d = blockIdx.x * 256 + threadIdx.x;
    const int base = ((d >> 6) * 4 + ((d >> 4) & 3)) * 256 + b * 16 + (d & 15);
    float s = 0.f;
#pragma unroll
    for (int ky = 0; ky < 8; ++ky)
        s += part[(long long)ky * 294912 + base];
    out[(long long)b * 18432 + d] = s;
}

extern "C" void kernel_launch(void* const* d_in, const int* in_sizes, int n_in,
                              void* d_out, int out_size, void* d_ws, size_t ws_size,
                              hipStream_t stream)
{
    (void)in_sizes; (void)n_in; (void)out_size; (void)ws_size;
    const float* z_seq   = (const float*)d_in[0];
    const float* z_query = (const float*)d_in[1];
    const float* noise   = (const float*)d_in[2];
    const float* mm      = (const float*)d_in[3];
    const float* mlv     = (const float*)d_in[4];
    const float* wlv     = (const float*)d_in[5];
    const float* WM      = (const float*)d_in[6];
    float* out = (float*)d_out;   // [zr 32768 | Zrkv 294912 | dkl_M | dkl_w]

    char* wsb = (char*)d_ws;
    unsigned short* ztb  = (unsigned short*)(wsb);                  // 16 MB (B,S,C) bf16
    unsigned short* wTb  = (unsigned short*)(wsb + (16LL << 20));   // 4 MB (B,K,S) bf16
    float*          G1   = (float*)(wsb + (24LL << 20));            // 1 MB (K,K) f32
    unsigned short* P1b  = (unsigned short*)(wsb + (26LL << 20));   // 2 MB (C,K) bf16
    float*          pZ   = (float*)(wsb + (40LL << 20));            // 9.4 MB zrkv partials
    float*          vec  = (float*)(wsb + (52LL << 20));
    float* qvec     = vec;           // 4096
    float* wmean    = vec + 4096;    // 8192
    float* dklpart  = vec + 12288;   // 1024
    float* yP       = vec + 16384;   // 32768 [8][16][256]

    // 1. zt (bf16) + q = zt @ zq fused
    prep_zt_q_kernel<<<4096, 256, 0, stream>>>(z_seq, noise, z_query, ztb, qvec);
    // 2. G1 = mm @ mm^T   (512,512,2048)
    gemm_mfma<64,64,false,true,false,false,false><<<dim3(8,8,1),256,0,stream>>>(
        mm,2048,0, mm,2048,0, G1,512,0, nullptr,0, 1.f,0.f, 2048);
    // 3. P1 = 8a*mm^T - 28a^2*(mm^T @ G1) -> bf16  (2048,512,512)
    gemm_mfma<64,64,true,false,false,false,true,false,true><<<dim3(8,32,1),256,0,stream>>>(
        mm,2048,0, G1,512,0, P1b,512,0, mm,2048,
        -28.0f*ALPHA*ALPHA, 8.0f*ALPHA, 512);
    // 4. wT[b][k][s] = (zt @ P1)^T bf16  (4096,512,2048)
    gemm_mfma<128,64,false,false,true,true,true,true,false><<<dim3(8,32,1),256,0,stream>>>(
        ztb,2048,0, P1b,512,0, wTb,256,131072, nullptr,0, 1.f,0.f, 2048);
    // 5. nmm GEMM with fused dkl (nmm never materialized)
    nmm_dkl_kernel<<<dim3(16,4,16),256,0,stream>>>(wTb, ztb, mm, mlv, dklpart);
    // 6. wmean = 64a^2 * wT @ q
    u_kernel<<<dim3(32,16),256,0,stream>>>(wTb, qvec, wmean);
    // 7. y partials = wmean @ wT
    y_kernel<<<dim3(8,16),256,0,stream>>>(wTb, wmean, yP);
    // 8. z_retrieved = 8a * y @ zt, + dkl_M + dkl_w
    zret_fin_kernel<<<258,256,0,stream>>>(ztb, yP, dklpart, wmean, wlv, out);
    // 9-10. Z_r_kv = zr @ W^T (K-split 8 MFMA stream + combine)
    zrkv_mfma_kernel<<<dim3(288,8),256,0,stream>>>(WM, out, pZ);
    zrkv_combine_kernel<<<dim3(72,16),256,0,stream>>>(pZ, out + 32768);
}

// Round 9
// 198.384 us; speedup vs baseline: 1.3746x; 1.0232x over previous
//
#include <hip/hip_runtime.h>

#define ALPHA 5.0e-4f

typedef short s16x8 __attribute__((ext_vector_type(8)));
typedef unsigned short u16x8 __attribute__((ext_vector_type(8)));
typedef float f32x4 __attribute__((ext_vector_type(4)));

__device__ __forceinline__ unsigned short f2bf(float f) {
    unsigned int u = __builtin_bit_cast(unsigned int, f);
    u += 0x7fffu + ((u >> 16) & 1u);
    return (unsigned short)(u >> 16);
}
__device__ __forceinline__ float bf2f(unsigned short h) {
    return __builtin_bit_cast(float, (unsigned int)h << 16);
}
__device__ __forceinline__ f32x4 mfma16(s16x8 a, s16x8 b, f32x4 c) {
    return __builtin_amdgcn_mfma_f32_16x16x32_bf16(a, b, c, 0, 0, 0);
}

// ---------------------------------------------------------------------------
// Staging helpers -> LDS tile [ROWS][64 bf16], XOR-swizzled (slot ^= row&7).
// ---------------------------------------------------------------------------
template<int ROWS>
__device__ __forceinline__ void stage_kcontig(const float* __restrict__ src, int ld,
                                              unsigned short* __restrict__ lds, int tid)
{
#pragma unroll
    for (int it = 0; it < ROWS * 8 / 256; ++it) {
        const int g = tid + it * 256;
        const int row = g >> 3, s = g & 7;
        const float* p = src + (long long)row * ld + s * 8;
        const float4 x0 = *(const float4*)p;
        const float4 x1 = *(const float4*)(p + 4);
        u16x8 h;
        h[0] = f2bf(x0.x); h[1] = f2bf(x0.y); h[2] = f2bf(x0.z); h[3] = f2bf(x0.w);
        h[4] = f2bf(x1.x); h[5] = f2bf(x1.y); h[6] = f2bf(x1.z); h[7] = f2bf(x1.w);
        *(u16x8*)(lds + row * 64 + ((s ^ (row & 7)) << 3)) = h;
    }
}

template<int ROWS>
__device__ __forceinline__ void stage_kstrided(const float* __restrict__ src, int ld,
                                               unsigned short* __restrict__ lds, int tid)
{
    constexpr int KPT = ROWS * 64 / 256;
    const int m = tid % ROWS, kb = (tid / ROWS) * KPT;
#pragma unroll
    for (int j8 = 0; j8 < KPT / 8; ++j8) {
        u16x8 h;
#pragma unroll
        for (int j = 0; j < 8; ++j)
            h[j] = f2bf(src[(long long)(kb + j8 * 8 + j) * ld + m]);
        const int s = (kb >> 3) + j8;
        *(u16x8*)(lds + m * 64 + ((s ^ (m & 7)) << 3)) = h;
    }
}

template<int ROWS>
__device__ __forceinline__ void stage_kcontig_b(const unsigned short* __restrict__ src, int ld,
                                                unsigned short* __restrict__ lds, int tid)
{
#pragma unroll
    for (int it = 0; it < ROWS * 8 / 256; ++it) {
        const int g = tid + it * 256;
        const int row = g >> 3, s = g & 7;
        const u16x8 h = *(const u16x8*)(src + (long long)row * ld + s * 8);
        *(u16x8*)(lds + row * 64 + ((s ^ (row & 7)) << 3)) = h;
    }
}

template<int ROWS>
__device__ __forceinline__ void stage_kstrided_b(const unsigned short* __restrict__ src, int ld,
                                                 unsigned short* __restrict__ lds, int tid)
{
    constexpr int KPT = ROWS * 64 / 256;
    const int m = tid % ROWS, kb = (tid / ROWS) * KPT;
#pragma unroll
    for (int j8 = 0; j8 < KPT / 8; ++j8) {
        u16x8 h;
#pragma unroll
        for (int j = 0; j < 8; ++j)
            h[j] = src[(long long)(kb + j8 * 8 + j) * ld + m];
        const int s = (kb >> 3) + j8;
        *(u16x8*)(lds + m * 64 + ((s ^ (m & 7)) << 3)) = h;
    }
}

// ---------------------------------------------------------------------------
// GEMM device body:  D = alpha*op(A)@op(B) + beta*Cin
// ---------------------------------------------------------------------------
template<int BM, int BN, bool TA, bool TB, bool ABF, bool BBF, bool OBF,
         bool OT, bool CINT>
__device__ __forceinline__
void gemm_dev(int bx, int by, int bz,
              const void* __restrict__ Av, int lda, long long sA,
              const void* __restrict__ Bv, int ldb, long long sB,
              void* __restrict__ Dv, int ldd, long long sD,
              const float* __restrict__ Cin, long long sC,
              float alpha, float beta, int Kd)
{
    constexpr int TWM = BM / 2, TWN = BN / 2;
    constexpr int FM = TWM / 16, FN = TWN / 16;
    __shared__ unsigned short As[BM * 64];
    __shared__ unsigned short Bs[BN * 64];

    const int tid = threadIdx.x;
    const int lane = tid & 63, w = tid >> 6;
    const int wm = w >> 1, wn = w & 1;
    const int lrow = lane & 15, lk = lane >> 4;
    const int m0 = by * BM, n0 = bx * BN;

    f32x4 acc[FM][FN];
#pragma unroll
    for (int i = 0; i < FM; ++i)
#pragma unroll
        for (int j = 0; j < FN; ++j) acc[i][j] = (f32x4){0.f, 0.f, 0.f, 0.f};

    for (int k0 = 0; k0 < Kd; k0 += 64) {
        if (ABF) {
            const unsigned short* Ab = (const unsigned short*)Av + (long long)bz * sA;
            if (!TA) stage_kcontig_b<BM>(Ab + (long long)m0 * lda + k0, lda, As, tid);
            else     stage_kstrided_b<BM>(Ab + (long long)k0 * lda + m0, lda, As, tid);
        } else {
            const float* Ab = (const float*)Av + (long long)bz * sA;
            if (!TA) stage_kcontig<BM>(Ab + (long long)m0 * lda + k0, lda, As, tid);
            else     stage_kstrided<BM>(Ab + (long long)k0 * lda + m0, lda, As, tid);
        }
        if (BBF) {
            const unsigned short* Bb = (const unsigned short*)Bv + (long long)bz * sB;
            if (TB)  stage_kcontig_b<BN>(Bb + (long long)n0 * ldb + k0, ldb, Bs, tid);
            else     stage_kstrided_b<BN>(Bb + (long long)k0 * ldb + n0, ldb, Bs, tid);
        } else {
            const float* Bb = (const float*)Bv + (long long)bz * sB;
            if (TB)  stage_kcontig<BN>(Bb + (long long)n0 * ldb + k0, ldb, Bs, tid);
            else     stage_kstrided<BN>(Bb + (long long)k0 * ldb + n0, ldb, Bs, tid);
        }
        __syncthreads();
#pragma unroll
        for (int kk = 0; kk < 2; ++kk) {
            s16x8 ah[FM], bh[FN];
#pragma unroll
            for (int i = 0; i < FM; ++i) {
                const int row = wm * TWM + i * 16 + lrow;
                const int s = kk * 4 + lk;
                ah[i] = *(const s16x8*)(As + row * 64 + ((s ^ (row & 7)) << 3));
            }
#pragma unroll
            for (int j = 0; j < FN; ++j) {
                const int col = wn * TWN + j * 16 + lrow;
                const int s = kk * 4 + lk;
                bh[j] = *(const s16x8*)(Bs + col * 64 + ((s ^ (col & 7)) << 3));
            }
#pragma unroll
            for (int i = 0; i < FM; ++i)
#pragma unroll
                for (int j = 0; j < FN; ++j)
                    acc[i][j] = mfma16(ah[i], bh[j], acc[i][j]);
        }
        __syncthreads();
    }

#pragma unroll
    for (int i = 0; i < FM; ++i)
#pragma unroll
        for (int j = 0; j < FN; ++j) {
            const int col = n0 + wn * TWN + j * 16 + lrow;
#pragma unroll
            for (int r = 0; r < 4; ++r) {
                const int row = m0 + wm * TWM + i * 16 + lk * 4 + r;
                float v = alpha * acc[i][j][r];
                if (Cin) {
                    const float cv = CINT ? Cin[(long long)col * sC + row]
                                          : Cin[(long long)row * ldd + col];
                    v = fmaf(beta, cv, v);
                }
                if (OT) {
                    ((unsigned short*)Dv)[(long long)(row >> 8) * sD +
                                          (long long)col * ldd + (row & 255)] = f2bf(v);
                } else if (OBF) {
                    ((unsigned short*)Dv + (long long)bz * sD)[(long long)row * ldd + col] = f2bf(v);
                } else {
                    ((float*)Dv + (long long)bz * sD)[(long long)row * ldd + col] = v;
                }
            }
        }
}

template<int BM, int BN, bool TA, bool TB, bool ABF, bool BBF, bool OBF,
         bool OT = false, bool CINT = false>
__global__ __launch_bounds__(256)
void gemm_mfma(const void* __restrict__ Av, int lda, long long sA,
               const void* __restrict__ Bv, int ldb, long long sB,
               void* __restrict__ Dv, int ldd, long long sD,
               const float* __restrict__ Cin, long long sC,
               float alpha, float beta, int Kd)
{
    gemm_dev<BM, BN, TA, TB, ABF, BBF, OBF, OT, CINT>(
        blockIdx.x, blockIdx.y, blockIdx.z,
        Av, lda, sA, Bv, ldb, sB, Dv, ldd, sD, Cin, sC, alpha, beta, Kd);
}

// ---------------------------------------------------------------------------
// fused_prep: blocks 0..4095: zt/q prep; 4096..4159: G1 GEMM; 4160: zero-init.
// ---------------------------------------------------------------------------
__global__ __launch_bounds__(256)
void fused_prep_kernel(const float* __restrict__ zs, const float* __restrict__ no,
                       const float* __restrict__ zq, const float* __restrict__ mm,
                       unsigned short* __restrict__ ztb, float* __restrict__ q,
                       float* __restrict__ G1, float* __restrict__ wmean,
                       float* __restrict__ out)
{
    const int blk = blockIdx.x, t = threadIdx.x;
    if (blk < 4096) {
        const int bs = blk;                 // b*256 + s
        const int b = bs >> 8, sI = bs & 255;
        const long long in = ((long long)sI * 16 + b) * 2048 + t * 8;
        const f32x4 z0 = __builtin_nontemporal_load((const f32x4*)(zs + in));
        const f32x4 z1 = __builtin_nontemporal_load((const f32x4*)(zs + in + 4));
        const f32x4 n0 = __builtin_nontemporal_load((const f32x4*)(no + in));
        const f32x4 n1 = __builtin_nontemporal_load((const f32x4*)(no + in + 4));
        float zf[8];
#pragma unroll
        for (int j = 0; j < 4; ++j) {
            zf[j]     = fmaf(0.01f, n0[j], z0[j]);
            zf[j + 4] = fmaf(0.01f, n1[j], z1[j]);
        }
        u16x8 o;
#pragma unroll
        for (int j = 0; j < 8; ++j) o[j] = f2bf(zf[j]);
        *(u16x8*)(ztb + ((long long)bs * 2048 + t * 8)) = o;
        const float4 q0 = *(const float4*)(zq + b * 2048 + t * 8);
        const float4 q1 = *(const float4*)(zq + b * 2048 + t * 8 + 4);
        float qa = zf[0] * q0.x + zf[1] * q0.y + zf[2] * q0.z + zf[3] * q0.w
                 + zf[4] * q1.x + zf[5] * q1.y + zf[6] * q1.z + zf[7] * q1.w;
        __shared__ float red[256];
        red[t] = qa; __syncthreads();
        for (int st = 128; st > 0; st >>= 1) { if (t < st) red[t] += red[t + st]; __syncthreads(); }
        if (t == 0) q[bs] = red[0];
    } else if (blk < 4160) {
        const int g = blk - 4096;
        gemm_dev<64, 64, false, true, false, false, false, false, false>(
            g & 7, g >> 3, 0, mm, 2048, 0, mm, 2048, 0, G1, 512, 0,
            nullptr, 0, 1.f, 0.f, 2048);
    } else {
        for (int i = t; i < 8192; i += 256) wmean[i] = 0.f;
        if (t == 0) out[327680] = 0.f;
    }
}

// ---------------------------------------------------------------------------
// wT GEMM (zt @ P1 -> bf16 transposed) + fused u: wmean += 64a^2 * w^T q.
// BM=128, BN=64, grid (8,32).
// ---------------------------------------------------------------------------
__global__ __launch_bounds__(256)
void wT_u_kernel(const unsigned short* __restrict__ ztb,
                 const unsigned short* __restrict__ P1b,
                 unsigned short* __restrict__ wTb,
                 const float* __restrict__ q, float* __restrict__ wmean)
{
    constexpr int BM = 128, BN = 64, TWM = 64, TWN = 32, FM = 4, FN = 2;
    __shared__ unsigned short As[BM * 64];
    __shared__ unsigned short Bs[BN * 64];
    const int bx = blockIdx.x, by = blockIdx.y;
    const int tid = threadIdx.x;
    const int lane = tid & 63, w = tid >> 6;
    const int wm = w >> 1, wn = w & 1;
    const int lrow = lane & 15, lk = lane >> 4;
    const int m0 = by * BM, n0 = bx * BN;

    f32x4 acc[FM][FN];
#pragma unroll
    for (int i = 0; i < FM; ++i)
#pragma unroll
        for (int j = 0; j < FN; ++j) acc[i][j] = (f32x4){0.f, 0.f, 0.f, 0.f};

    for (int k0 = 0; k0 < 2048; k0 += 64) {
        stage_kcontig_b<BM>(ztb + (long long)m0 * 2048 + k0, 2048, As, tid);
        stage_kstrided_b<BN>(P1b + (long long)k0 * 512 + n0, 512, Bs, tid);
        __syncthreads();
#pragma unroll
        for (int kk = 0; kk < 2; ++kk) {
            s16x8 ah[FM], bh[FN];
#pragma unroll
            for (int i = 0; i < FM; ++i) {
                const int row = wm * TWM + i * 16 + lrow;
                const int s = kk * 4 + lk;
                ah[i] = *(const s16x8*)(As + row * 64 + ((s ^ (row & 7)) << 3));
            }
#pragma unroll
            for (int j = 0; j < FN; ++j) {
                const int col = wn * TWN + j * 16 + lrow;
                const int s = kk * 4 + lk;
                bh[j] = *(const s16x8*)(Bs + col * 64 + ((s ^ (col & 7)) << 3));
            }
#pragma unroll
            for (int i = 0; i < FM; ++i)
#pragma unroll
                for (int j = 0; j < FN; ++j)
                    acc[i][j] = mfma16(ah[i], bh[j], acc[i][j]);
        }
        __syncthreads();
    }

    float up[FN] = {0.f, 0.f};
#pragma unroll
    for (int i = 0; i < FM; ++i)
#pragma unroll
        for (int r = 0; r < 4; ++r) {
            const int row = m0 + wm * TWM + i * 16 + lk * 4 + r;
            const float qv = q[row];
#pragma unroll
            for (int j = 0; j < FN; ++j) {
                const int col = n0 + wn * TWN + j * 16 + lrow;
                const float v = acc[i][j][r];
                wTb[(long long)(row >> 8) * 131072 + (long long)col * 256 + (row & 255)] = f2bf(v);
                up[j] = fmaf(v, qv, up[j]);
            }
        }
    const int b = m0 >> 8;
#pragma unroll
    for (int j = 0; j < FN; ++j) {
        float v = up[j];
        v += __shfl_xor(v, 16);
        v += __shfl_xor(v, 32);
        if (lk == 0) {
            const int col = n0 + wn * TWN + j * 16 + lrow;
            atomicAdd(&wmean[b * 512 + col], (64.0f * ALPHA * ALPHA) * v);
        }
    }
}

// ---------------------------------------------------------------------------
// tail: blocks 0..1023 nmm_dkl (atomicAdd dkl_M); 1024..1279 zret (y recompute);
//       1280 dkl_w.
// ---------------------------------------------------------------------------
__global__ __launch_bounds__(256)
void tail_kernel(const unsigned short* __restrict__ wTb,
                 const unsigned short* __restrict__ ztb,
                 const float* __restrict__ mm, const float* __restrict__ mlv,
                 const float* __restrict__ wmean, const float* __restrict__ wlv,
                 float* __restrict__ out)
{
    __shared__ __align__(16) unsigned char smem[34304];
    const int blk = blockIdx.x, tid = threadIdx.x;
    if (blk < 1024) {
        constexpr int BM = 128, BN = 128, TWM = 64, TWN = 64, FM = 4, FN = 4;
        unsigned short* As = (unsigned short*)smem;               // 16384 B
        unsigned short* Bs = As + BM * 64;                        // 16384 B
        float* ivars = (float*)(smem + 32768);                    // 512 B
        float* red = (float*)(smem + 33280);                      // 1024 B
        const int bx = blk & 15, by = (blk >> 4) & 3, bz = blk >> 6;
        const int lane = tid & 63, w = tid >> 6;
        const int wm = w >> 1, wn = w & 1;
        const int lrow = lane & 15, lk = lane >> 4;
        const int m0 = by * BM, n0 = bx * BN;

        if (tid < 128) ivars[tid] = 1.0f / (expf(mlv[m0 + tid]) + 1e-6f);

        f32x4 acc[FM][FN];
#pragma unroll
        for (int i = 0; i < FM; ++i)
#pragma unroll
            for (int j = 0; j < FN; ++j) acc[i][j] = (f32x4){0.f, 0.f, 0.f, 0.f};

        for (int k0 = 0; k0 < 256; k0 += 64) {
            stage_kcontig_b<BM>(wTb + (long long)bz * 131072 + (long long)m0 * 256 + k0, 256, As, tid);
            stage_kstrided_b<BN>(ztb + (long long)bz * 524288 + (long long)k0 * 2048 + n0, 2048, Bs, tid);
            __syncthreads();
#pragma unroll
            for (int kk = 0; kk < 2; ++kk) {
                s16x8 ah[FM], bh[FN];
#pragma unroll
                for (int i = 0; i < FM; ++i) {
                    const int row = wm * TWM + i * 16 + lrow;
                    const int s = kk * 4 + lk;
                    ah[i] = *(const s16x8*)(As + row * 64 + ((s ^ (row & 7)) << 3));
                }
#pragma unroll
                for (int j = 0; j < FN; ++j) {
                    const int col = wn * TWN + j * 16 + lrow;
                    const int s = kk * 4 + lk;
                    bh[j] = *(const s16x8*)(Bs + col * 64 + ((s ^ (col & 7)) << 3));
                }
#pragma unroll
                for (int i = 0; i < FM; ++i)
#pragma unroll
                    for (int j = 0; j < FN; ++j)
                        acc[i][j] = mfma16(ah[i], bh[j], acc[i][j]);
            }
            __syncthreads();
        }

        const float A8 = 8.0f * ALPHA;
        float da = 0.f;
#pragma unroll
        for (int i = 0; i < FM; ++i)
#pragma unroll
            for (int j = 0; j < FN; ++j) {
                const int cl = wn * TWN + j * 16 + lrow;
#pragma unroll
                for (int r = 0; r < 4; ++r) {
                    const int rl = wm * TWM + i * 16 + lk * 4 + r;
                    const float v = A8 * acc[i][j][r];
                    const float d = v - mm[(long long)(m0 + rl) * 2048 + (n0 + cl)];
                    da = fmaf(d * d, ivars[rl], da);
                }
            }
        red[tid] = da; __syncthreads();
        for (int st = 128; st > 0; st >>= 1) { if (tid < st) red[tid] += red[tid + st]; __syncthreads(); }
        if (tid == 0) atomicAdd(&out[327680], red[0] * (1.0f / 16.0f));
    } else if (blk < 1280) {
        float* wms = (float*)smem;               // 2048 B
        float* ys  = (float*)(smem + 2048);      // 1024 B
        float* red2 = (float*)(smem + 3072);     // 1024 B
        const int idx = blk - 1024, b = idx & 15, ct = idx >> 4;
        wms[tid] = wmean[b * 512 + tid];
        wms[tid + 256] = wmean[b * 512 + 256 + tid];
        __syncthreads();
        {
            const unsigned short* wp = wTb + (long long)b * 131072 + tid;
            float yv = 0.f;
#pragma unroll 8
            for (int k = 0; k < 512; ++k)
                yv = fmaf(wms[k], bf2f(wp[(long long)k * 256]), yv);
            ys[tid] = yv;
        }
        __syncthreads();
        const int c = ct * 128 + (tid & 127), sh = tid >> 7;
        const unsigned short* zp = ztb + (long long)b * 524288 + c;
        float acc2 = 0.f;
        const int sbase = sh * 128;
#pragma unroll 8
        for (int s = 0; s < 128; ++s)
            acc2 = fmaf(ys[sbase + s], bf2f(zp[(long long)(sbase + s) * 2048]), acc2);
        red2[tid] = acc2; __syncthreads();
        if (sh == 0)
            out[(long long)b * 2048 + c] = (8.0f * ALPHA) * (red2[tid] + red2[tid + 128]);
    } else {
        float* red = (float*)smem;
        float s = 0.f;
        for (int i = tid; i < 16 * 512; i += 256) { const float v = wmean[i]; s += v * v; }
        red[tid] = s; __syncthreads();
        for (int st = 128; st > 0; st >>= 1) { if (tid < st) red[tid] += red[tid + st]; __syncthreads(); }
        if (tid == 0) {
            const float l = wlv[0];
            out[327681] = 0.5f * (red[0] + 8192.0f * (expf(l) - 1.0f - l));
        }
    }
}

// ---------------------------------------------------------------------------
// Z_r_kv partials: M=16 b, N=18432 d, K=2048, K-split 8 -> grid (288, 8).
// W loads NON-TEMPORAL. Store layout: 64B-contiguous runs per wave.
// ---------------------------------------------------------------------------
__global__ __launch_bounds__(256)
void zrkv_mfma_kernel(const float* __restrict__ W, const float* __restrict__ zr,
                      float* __restrict__ part)
{
    const int tid = threadIdx.x, lane = tid & 63, w = tid >> 6;
    const int bx = blockIdx.x, ky = blockIdx.y;
    const int d0 = bx * 64 + w * 16;
    const int kc0 = ky * 256;
    const int rr = lane & 15, kq = lane >> 4;
    s16x8 areg[8];
    const float* zb = zr + rr * 2048 + kc0 + kq * 8;
#pragma unroll
    for (int s = 0; s < 8; ++s) {
        const f32x4 a0 = *(const f32x4*)(zb + s * 32);
        const f32x4 a1 = *(const f32x4*)(zb + s * 32 + 4);
        u16x8 h;
#pragma unroll
        for (int j = 0; j < 4; ++j) { h[j] = f2bf(a0[j]); h[j + 4] = f2bf(a1[j]); }
        areg[s] = __builtin_bit_cast(s16x8, h);
    }
    f32x4 acc = {0.f, 0.f, 0.f, 0.f};
    const float* wb = W + (long long)(d0 + rr) * 2048 + kc0 + kq * 8;
#pragma unroll
    for (int s = 0; s < 8; ++s) {
        const f32x4 b0 = __builtin_nontemporal_load((const f32x4*)(wb + s * 32));
        const f32x4 b1 = __builtin_nontemporal_load((const f32x4*)(wb + s * 32 + 4));
        u16x8 h;
#pragma unroll
        for (int j = 0; j < 4; ++j) { h[j] = f2bf(b0[j]); h[j + 4] = f2bf(b1[j]); }
        acc = mfma16(areg[s], __builtin_bit_cast(s16x8, h), acc);
    }
    float* pb = part + (((long long)ky * 288 + bx) * 4 + w) * 256 + kq * 64 + rr;
#pragma unroll
    for (int r = 0; r < 4; ++r) pb[r * 16] = acc[r];
}

// out[b*18432+d] = sum_ky part[...]   grid (72, 16)
__global__ __launch_bounds__(256)
void zrkv_combine_kernel(const float* __restrict__ part, float* __restrict__ out)
{
    const int b = blockIdx.y;
    const int d = blockIdx.x * 256 + threadIdx.x;
    const int base = ((d >> 6) * 4 + ((d >> 4) & 3)) * 256 + b * 16 + (d & 15);
    float s = 0.f;
#pragma unroll
    for (int ky = 0; ky < 8; ++ky)
        s += part[(long long)ky * 294912 + base];
    out[(long long)b * 18432 + d] = s;
}

extern "C" void kernel_launch(void* const* d_in, const int* in_sizes, int n_in,
                              void* d_out, int out_size, void* d_ws, size_t ws_size,
                              hipStream_t stream)
{
    (void)in_sizes; (void)n_in; (void)out_size; (void)ws_size;
    const float* z_seq   = (const float*)d_in[0];
    const float* z_query = (const float*)d_in[1];
    const float* noise   = (const float*)d_in[2];
    const float* mm      = (const float*)d_in[3];
    const float* mlv     = (const float*)d_in[4];
    const float* wlv     = (const float*)d_in[5];
    const float* WM      = (const float*)d_in[6];
    float* out = (float*)d_out;   // [zr 32768 | Zrkv 294912 | dkl_M | dkl_w]

    char* wsb = (char*)d_ws;
    unsigned short* ztb  = (unsigned short*)(wsb);                  // 16 MB (B,S,C) bf16
    unsigned short* wTb  = (unsigned short*)(wsb + (16LL << 20));   // 4 MB (B,K,S) bf16
    float*          G1   = (float*)(wsb + (24LL << 20));            // 1 MB (K,K) f32
    unsigned short* P1b  = (unsigned short*)(wsb + (26LL << 20));   // 2 MB (C,K) bf16
    float*          pZ   = (float*)(wsb + (40LL << 20));            // 9.4 MB zrkv partials
    float*          vec  = (float*)(wsb + (52LL << 20));
    float* qvec     = vec;           // 4096
    float* wmean    = vec + 4096;    // 8192

    // 1. prep (zt + q)  ||  G1 = mm @ mm^T  ||  zero-init wmean & dkl_M
    fused_prep_kernel<<<4161, 256, 0, stream>>>(z_seq, noise, z_query, mm,
                                                ztb, qvec, G1, wmean, out);
    // 2. P1 = 8a*mm^T - 28a^2*(mm^T @ G1) -> bf16  (2048,512,512)
    gemm_mfma<64,64,true,false,false,false,true,false,true><<<dim3(8,32,1),256,0,stream>>>(
        mm,2048,0, G1,512,0, P1b,512,0, mm,2048,
        -28.0f*ALPHA*ALPHA, 8.0f*ALPHA, 512);
    // 3. wT = (zt @ P1)^T bf16, + fused u -> wmean (atomics)
    wT_u_kernel<<<dim3(8,32),256,0,stream>>>(ztb, P1b, wTb, qvec, wmean);
    // 4. nmm+dkl_M  ||  zret (y recompute)  ||  dkl_w
    tail_kernel<<<1281,256,0,stream>>>(wTb, ztb, mm, mlv, wmean, wlv, out);
    // 5-6. Z_r_kv = zr @ W^T (K-split 8 MFMA stream + combine)
    zrkv_mfma_kernel<<<dim3(288,8),256,0,stream>>>(WM, out, pZ);
    zrkv_combine_kernel<<<dim3(72,16),256,0,stream>>>(pZ, out + 32768);
}

// Round 10
// 181.443 us; speedup vs baseline: 1.5030x; 1.0934x over previous
//
#include <hip/hip_runtime.h>

#define ALPHA 5.0e-4f

typedef short s16x8 __attribute__((ext_vector_type(8)));
typedef unsigned short u16x8 __attribute__((ext_vector_type(8)));
typedef float f32x4 __attribute__((ext_vector_type(4)));

__device__ __forceinline__ unsigned short f2bf(float f) {
    unsigned int u = __builtin_bit_cast(unsigned int, f);
    u += 0x7fffu + ((u >> 16) & 1u);
    return (unsigned short)(u >> 16);
}
__device__ __forceinline__ float bf2f(unsigned short h) {
    return __builtin_bit_cast(float, (unsigned int)h << 16);
}
__device__ __forceinline__ f32x4 mfma16(s16x8 a, s16x8 b, f32x4 c) {
    return __builtin_amdgcn_mfma_f32_16x16x32_bf16(a, b, c, 0, 0, 0);
}

// ---------------------------------------------------------------------------
// Staging helpers -> LDS tile [ROWS][64 bf16], XOR-swizzled (slot ^= row&7).
// ---------------------------------------------------------------------------
template<int ROWS>
__device__ __forceinline__ void stage_kcontig(const float* __restrict__ src, int ld,
                                              unsigned short* __restrict__ lds, int tid)
{
#pragma unroll
    for (int it = 0; it < ROWS * 8 / 256; ++it) {
        const int g = tid + it * 256;
        const int row = g >> 3, s = g & 7;
        const float* p = src + (long long)row * ld + s * 8;
        const float4 x0 = *(const float4*)p;
        const float4 x1 = *(const float4*)(p + 4);
        u16x8 h;
        h[0] = f2bf(x0.x); h[1] = f2bf(x0.y); h[2] = f2bf(x0.z); h[3] = f2bf(x0.w);
        h[4] = f2bf(x1.x); h[5] = f2bf(x1.y); h[6] = f2bf(x1.z); h[7] = f2bf(x1.w);
        *(u16x8*)(lds + row * 64 + ((s ^ (row & 7)) << 3)) = h;
    }
}

template<int ROWS>
__device__ __forceinline__ void stage_kstrided(const float* __restrict__ src, int ld,
                                               unsigned short* __restrict__ lds, int tid)
{
    constexpr int KPT = ROWS * 64 / 256;
    const int m = tid % ROWS, kb = (tid / ROWS) * KPT;
#pragma unroll
    for (int j8 = 0; j8 < KPT / 8; ++j8) {
        u16x8 h;
#pragma unroll
        for (int j = 0; j < 8; ++j)
            h[j] = f2bf(src[(long long)(kb + j8 * 8 + j) * ld + m]);
        const int s = (kb >> 3) + j8;
        *(u16x8*)(lds + m * 64 + ((s ^ (m & 7)) << 3)) = h;
    }
}

template<int ROWS>
__device__ __forceinline__ void stage_kcontig_b(const unsigned short* __restrict__ src, int ld,
                                                unsigned short* __restrict__ lds, int tid)
{
#pragma unroll
    for (int it = 0; it < ROWS * 8 / 256; ++it) {
        const int g = tid + it * 256;
        const int row = g >> 3, s = g & 7;
        const u16x8 h = *(const u16x8*)(src + (long long)row * ld + s * 8);
        *(u16x8*)(lds + row * 64 + ((s ^ (row & 7)) << 3)) = h;
    }
}

template<int ROWS>
__device__ __forceinline__ void stage_kstrided_b(const unsigned short* __restrict__ src, int ld,
                                                 unsigned short* __restrict__ lds, int tid)
{
    constexpr int KPT = ROWS * 64 / 256;
    const int m = tid % ROWS, kb = (tid / ROWS) * KPT;
#pragma unroll
    for (int j8 = 0; j8 < KPT / 8; ++j8) {
        u16x8 h;
#pragma unroll
        for (int j = 0; j < 8; ++j)
            h[j] = src[(long long)(kb + j8 * 8 + j) * ld + m];
        const int s = (kb >> 3) + j8;
        *(u16x8*)(lds + m * 64 + ((s ^ (m & 7)) << 3)) = h;
    }
}

// ---------------------------------------------------------------------------
// GEMM device body:  D = alpha*op(A)@op(B) + beta*Cin   (ATOM: atomicAdd f32)
// ---------------------------------------------------------------------------
template<int BM, int BN, bool TA, bool TB, bool ABF, bool BBF, bool OBF,
         bool OT, bool CINT, bool ATOM = false>
__device__ __forceinline__
void gemm_dev(int bx, int by, int bz,
              const void* __restrict__ Av, int lda, long long sA,
              const void* __restrict__ Bv, int ldb, long long sB,
              void* __restrict__ Dv, int ldd, long long sD,
              const float* __restrict__ Cin, long long sC,
              float alpha, float beta, int Kd)
{
    constexpr int TWM = BM / 2, TWN = BN / 2;
    constexpr int FM = TWM / 16, FN = TWN / 16;
    __shared__ unsigned short As[BM * 64];
    __shared__ unsigned short Bs[BN * 64];

    const int tid = threadIdx.x;
    const int lane = tid & 63, w = tid >> 6;
    const int wm = w >> 1, wn = w & 1;
    const int lrow = lane & 15, lk = lane >> 4;
    const int m0 = by * BM, n0 = bx * BN;

    f32x4 acc[FM][FN];
#pragma unroll
    for (int i = 0; i < FM; ++i)
#pragma unroll
        for (int j = 0; j < FN; ++j) acc[i][j] = (f32x4){0.f, 0.f, 0.f, 0.f};

    for (int k0 = 0; k0 < Kd; k0 += 64) {
        if (ABF) {
            const unsigned short* Ab = (const unsigned short*)Av + (long long)bz * sA;
            if (!TA) stage_kcontig_b<BM>(Ab + (long long)m0 * lda + k0, lda, As, tid);
            else     stage_kstrided_b<BM>(Ab + (long long)k0 * lda + m0, lda, As, tid);
        } else {
            const float* Ab = (const float*)Av + (long long)bz * sA;
            if (!TA) stage_kcontig<BM>(Ab + (long long)m0 * lda + k0, lda, As, tid);
            else     stage_kstrided<BM>(Ab + (long long)k0 * lda + m0, lda, As, tid);
        }
        if (BBF) {
            const unsigned short* Bb = (const unsigned short*)Bv + (long long)bz * sB;
            if (TB)  stage_kcontig_b<BN>(Bb + (long long)n0 * ldb + k0, ldb, Bs, tid);
            else     stage_kstrided_b<BN>(Bb + (long long)k0 * ldb + n0, ldb, Bs, tid);
        } else {
            const float* Bb = (const float*)Bv + (long long)bz * sB;
            if (TB)  stage_kcontig<BN>(Bb + (long long)n0 * ldb + k0, ldb, Bs, tid);
            else     stage_kstrided<BN>(Bb + (long long)k0 * ldb + n0, ldb, Bs, tid);
        }
        __syncthreads();
#pragma unroll
        for (int kk = 0; kk < 2; ++kk) {
            s16x8 ah[FM], bh[FN];
#pragma unroll
            for (int i = 0; i < FM; ++i) {
                const int row = wm * TWM + i * 16 + lrow;
                const int s = kk * 4 + lk;
                ah[i] = *(const s16x8*)(As + row * 64 + ((s ^ (row & 7)) << 3));
            }
#pragma unroll
            for (int j = 0; j < FN; ++j) {
                const int col = wn * TWN + j * 16 + lrow;
                const int s = kk * 4 + lk;
                bh[j] = *(const s16x8*)(Bs + col * 64 + ((s ^ (col & 7)) << 3));
            }
#pragma unroll
            for (int i = 0; i < FM; ++i)
#pragma unroll
                for (int j = 0; j < FN; ++j)
                    acc[i][j] = mfma16(ah[i], bh[j], acc[i][j]);
        }
        __syncthreads();
    }

#pragma unroll
    for (int i = 0; i < FM; ++i)
#pragma unroll
        for (int j = 0; j < FN; ++j) {
            const int col = n0 + wn * TWN + j * 16 + lrow;
#pragma unroll
            for (int r = 0; r < 4; ++r) {
                const int row = m0 + wm * TWM + i * 16 + lk * 4 + r;
                float v = alpha * acc[i][j][r];
                if (Cin) {
                    const float cv = CINT ? Cin[(long long)col * sC + row]
                                          : Cin[(long long)row * ldd + col];
                    v = fmaf(beta, cv, v);
                }
                if (ATOM) {
                    atomicAdd((float*)Dv + (long long)row * ldd + col, v);
                } else if (OT) {
                    ((unsigned short*)Dv)[(long long)(row >> 8) * sD +
                                          (long long)col * ldd + (row & 255)] = f2bf(v);
                } else if (OBF) {
                    ((unsigned short*)Dv + (long long)bz * sD)[(long long)row * ldd + col] = f2bf(v);
                } else {
                    ((float*)Dv + (long long)bz * sD)[(long long)row * ldd + col] = v;
                }
            }
        }
}

template<int BM, int BN, bool TA, bool TB, bool ABF, bool BBF, bool OBF,
         bool OT = false, bool CINT = false>
__global__ __launch_bounds__(256)
void gemm_mfma(const void* __restrict__ Av, int lda, long long sA,
               const void* __restrict__ Bv, int ldb, long long sB,
               void* __restrict__ Dv, int ldd, long long sD,
               const float* __restrict__ Cin, long long sC,
               float alpha, float beta, int Kd)
{
    gemm_dev<BM, BN, TA, TB, ABF, BBF, OBF, OT, CINT>(
        blockIdx.x, blockIdx.y, blockIdx.z,
        Av, lda, sA, Bv, ldb, sB, Dv, ldd, sD, Cin, sC, alpha, beta, Kd);
}

// ---------------------------------------------------------------------------
// fused_prep: blocks 0..4095: zt/q prep; 4096..4607: G1 K-split-8 partial GEMM
// (atomicAdd into pre-zeroed G1; ky = g&7 pins each K-slice to one XCD).
// ---------------------------------------------------------------------------
__global__ __launch_bounds__(256)
void fused_prep_kernel(const float* __restrict__ zs, const float* __restrict__ no,
                       const float* __restrict__ zq, const float* __restrict__ mm,
                       unsigned short* __restrict__ ztb, float* __restrict__ q,
                       float* __restrict__ G1)
{
    const int blk = blockIdx.x, t = threadIdx.x;
    if (blk < 4096) {
        const int bs = blk;                 // b*256 + s
        const int b = bs >> 8, sI = bs & 255;
        const long long in = ((long long)sI * 16 + b) * 2048 + t * 8;
        const f32x4 z0 = __builtin_nontemporal_load((const f32x4*)(zs + in));
        const f32x4 z1 = __builtin_nontemporal_load((const f32x4*)(zs + in + 4));
        const f32x4 n0 = __builtin_nontemporal_load((const f32x4*)(no + in));
        const f32x4 n1 = __builtin_nontemporal_load((const f32x4*)(no + in + 4));
        float zf[8];
#pragma unroll
        for (int j = 0; j < 4; ++j) {
            zf[j]     = fmaf(0.01f, n0[j], z0[j]);
            zf[j + 4] = fmaf(0.01f, n1[j], z1[j]);
        }
        u16x8 o;
#pragma unroll
        for (int j = 0; j < 8; ++j) o[j] = f2bf(zf[j]);
        *(u16x8*)(ztb + ((long long)bs * 2048 + t * 8)) = o;
        const float4 q0 = *(const float4*)(zq + b * 2048 + t * 8);
        const float4 q1 = *(const float4*)(zq + b * 2048 + t * 8 + 4);
        float qa = zf[0] * q0.x + zf[1] * q0.y + zf[2] * q0.z + zf[3] * q0.w
                 + zf[4] * q1.x + zf[5] * q1.y + zf[6] * q1.z + zf[7] * q1.w;
        __shared__ float red[256];
        red[t] = qa; __syncthreads();
        for (int st = 128; st > 0; st >>= 1) { if (t < st) red[t] += red[t + st]; __syncthreads(); }
        if (t == 0) q[bs] = red[0];
    } else {
        const int g = blk - 4096;           // 0..511
        const int ky = g & 7;               // K-chunk, XCD-pinned
        const int tile = g >> 3;            // 0..63
        gemm_dev<64, 64, false, true, false, false, false, false, false, true>(
            tile & 7, tile >> 3, 0,
            mm + ky * 256, 2048, 0, mm + ky * 256, 2048, 0,
            G1, 512, 0, nullptr, 0, 1.f, 0.f, 256);
    }
}

// ---------------------------------------------------------------------------
// wT GEMM (zt @ P1 -> bf16 transposed) + fused u: wmean += 64a^2 * w^T q.
// 1D grid 256, XCD-pinned: by%8 == lin%8 so the 8 bx sharing an A-panel
// land on one XCD (ztb panel stays L2-local).
// ---------------------------------------------------------------------------
__global__ __launch_bounds__(256)
void wT_u_kernel(const unsigned short* __restrict__ ztb,
                 const unsigned short* __restrict__ P1b,
                 unsigned short* __restrict__ wTb,
                 const float* __restrict__ q, float* __restrict__ wmean)
{
    constexpr int BM = 128, BN = 64, TWM = 64, TWN = 32, FM = 4, FN = 2;
    __shared__ unsigned short As[BM * 64];
    __shared__ unsigned short Bs[BN * 64];
    const int lin = blockIdx.x;
    const int r = lin & 7, tt = lin >> 3;
    const int by = r + 8 * (tt & 3), bx = tt >> 2;
    const int tid = threadIdx.x;
    const int lane = tid & 63, w = tid >> 6;
    const int wm = w >> 1, wn = w & 1;
    const int lrow = lane & 15, lk = lane >> 4;
    const int m0 = by * BM, n0 = bx * BN;

    f32x4 acc[FM][FN];
#pragma unroll
    for (int i = 0; i < FM; ++i)
#pragma unroll
        for (int j = 0; j < FN; ++j) acc[i][j] = (f32x4){0.f, 0.f, 0.f, 0.f};

    for (int k0 = 0; k0 < 2048; k0 += 64) {
        stage_kcontig_b<BM>(ztb + (long long)m0 * 2048 + k0, 2048, As, tid);
        stage_kstrided_b<BN>(P1b + (long long)k0 * 512 + n0, 512, Bs, tid);
        __syncthreads();
#pragma unroll
        for (int kk = 0; kk < 2; ++kk) {
            s16x8 ah[FM], bh[FN];
#pragma unroll
            for (int i = 0; i < FM; ++i) {
                const int row = wm * TWM + i * 16 + lrow;
                const int s = kk * 4 + lk;
                ah[i] = *(const s16x8*)(As + row * 64 + ((s ^ (row & 7)) << 3));
            }
#pragma unroll
            for (int j = 0; j < FN; ++j) {
                const int col = wn * TWN + j * 16 + lrow;
                const int s = kk * 4 + lk;
                bh[j] = *(const s16x8*)(Bs + col * 64 + ((s ^ (col & 7)) << 3));
            }
#pragma unroll
            for (int i = 0; i < FM; ++i)
#pragma unroll
                for (int j = 0; j < FN; ++j)
                    acc[i][j] = mfma16(ah[i], bh[j], acc[i][j]);
        }
        __syncthreads();
    }

    float up[FN] = {0.f, 0.f};
#pragma unroll
    for (int i = 0; i < FM; ++i)
#pragma unroll
        for (int rr = 0; rr < 4; ++rr) {
            const int row = m0 + wm * TWM + i * 16 + lk * 4 + rr;
            const float qv = q[row];
#pragma unroll
            for (int j = 0; j < FN; ++j) {
                const int col = n0 + wn * TWN + j * 16 + lrow;
                const float v = acc[i][j][rr];
                wTb[(long long)(row >> 8) * 131072 + (long long)col * 256 + (row & 255)] = f2bf(v);
                up[j] = fmaf(v, qv, up[j]);
            }
        }
    const int b = m0 >> 8;
#pragma unroll
    for (int j = 0; j < FN; ++j) {
        float v = up[j];
        v += __shfl_xor(v, 16);
        v += __shfl_xor(v, 32);
        if (lk == 0) {
            const int col = n0 + wn * TWN + j * 16 + lrow;
            atomicAdd(&wmean[b * 512 + col], (64.0f * ALPHA * ALPHA) * v);
        }
    }
}

// ---------------------------------------------------------------------------
// tail: blocks 0..1023 nmm+dkl (XCD-pinned by bz); 1024..1279 zret (pinned by b);
//       1280 dkl_w.
// ---------------------------------------------------------------------------
__global__ __launch_bounds__(256)
void tail_kernel(const unsigned short* __restrict__ wTb,
                 const unsigned short* __restrict__ ztb,
                 const float* __restrict__ mm, const float* __restrict__ mlv,
                 const float* __restrict__ wmean, const float* __restrict__ wlv,
                 float* __restrict__ out)
{
    __shared__ __align__(16) unsigned char smem[34304];
    const int blk = blockIdx.x, tid = threadIdx.x;
    if (blk < 1024) {
        constexpr int BM = 128, BN = 128, TWM = 64, TWN = 64, FM = 4, FN = 4;
        unsigned short* As = (unsigned short*)smem;               // 16384 B
        unsigned short* Bs = As + BM * 64;                        // 16384 B
        float* ivars = (float*)(smem + 32768);                    // 512 B
        float* red = (float*)(smem + 33280);                      // 1024 B
        const int r8 = blk & 7, t8 = blk >> 3;                    // XCD pin: bz
        const int bz = r8 + 8 * (t8 & 1);
        const int rest = t8 >> 1;                                 // 0..63
        const int by = rest & 3, bx = rest >> 2;
        const int lane = tid & 63, w = tid >> 6;
        const int wm = w >> 1, wn = w & 1;
        const int lrow = lane & 15, lk = lane >> 4;
        const int m0 = by * BM, n0 = bx * BN;

        if (tid < 128) ivars[tid] = 1.0f / (expf(mlv[m0 + tid]) + 1e-6f);

        f32x4 acc[FM][FN];
#pragma unroll
        for (int i = 0; i < FM; ++i)
#pragma unroll
            for (int j = 0; j < FN; ++j) acc[i][j] = (f32x4){0.f, 0.f, 0.f, 0.f};

        for (int k0 = 0; k0 < 256; k0 += 64) {
            stage_kcontig_b<BM>(wTb + (long long)bz * 131072 + (long long)m0 * 256 + k0, 256, As, tid);
            stage_kstrided_b<BN>(ztb + (long long)bz * 524288 + (long long)k0 * 2048 + n0, 2048, Bs, tid);
            __syncthreads();
#pragma unroll
            for (int kk = 0; kk < 2; ++kk) {
                s16x8 ah[FM], bh[FN];
#pragma unroll
                for (int i = 0; i < FM; ++i) {
                    const int row = wm * TWM + i * 16 + lrow;
                    const int s = kk * 4 + lk;
                    ah[i] = *(const s16x8*)(As + row * 64 + ((s ^ (row & 7)) << 3));
                }
#pragma unroll
                for (int j = 0; j < FN; ++j) {
                    const int col = wn * TWN + j * 16 + lrow;
                    const int s = kk * 4 + lk;
                    bh[j] = *(const s16x8*)(Bs + col * 64 + ((s ^ (col & 7)) << 3));
                }
#pragma unroll
                for (int i = 0; i < FM; ++i)
#pragma unroll
                    for (int j = 0; j < FN; ++j)
                        acc[i][j] = mfma16(ah[i], bh[j], acc[i][j]);
            }
            __syncthreads();
        }

        const float A8 = 8.0f * ALPHA;
        float da = 0.f;
#pragma unroll
        for (int i = 0; i < FM; ++i)
#pragma unroll
            for (int j = 0; j < FN; ++j) {
                const int cl = wn * TWN + j * 16 + lrow;
#pragma unroll
                for (int rr = 0; rr < 4; ++rr) {
                    const int rl = wm * TWM + i * 16 + lk * 4 + rr;
                    const float v = A8 * acc[i][j][rr];
                    const float d = v - mm[(long long)(m0 + rl) * 2048 + (n0 + cl)];
                    da = fmaf(d * d, ivars[rl], da);
                }
            }
        red[tid] = da; __syncthreads();
        for (int st = 128; st > 0; st >>= 1) { if (tid < st) red[tid] += red[tid + st]; __syncthreads(); }
        if (tid == 0) atomicAdd(&out[327680], red[0] * (1.0f / 16.0f));
    } else if (blk < 1280) {
        float* wms = (float*)smem;               // 2048 B
        float* ys  = (float*)(smem + 2048);      // 1024 B
        float* red2 = (float*)(smem + 3072);     // 1024 B
        const int idx = blk - 1024;
        const int r8 = idx & 7, t8 = idx >> 3;
        const int b = r8 + 8 * (t8 & 1), ct = t8 >> 1;   // b XCD-pinned
        wms[tid] = wmean[b * 512 + tid];
        wms[tid + 256] = wmean[b * 512 + 256 + tid];
        __syncthreads();
        {
            const unsigned short* wp = wTb + (long long)b * 131072 + tid;
            float yv = 0.f;
#pragma unroll 8
            for (int k = 0; k < 512; ++k)
                yv = fmaf(wms[k], bf2f(wp[(long long)k * 256]), yv);
            ys[tid] = yv;
        }
        __syncthreads();
        const int c = ct * 128 + (tid & 127), sh = tid >> 7;
        const unsigned short* zp = ztb + (long long)b * 524288 + c;
        float acc2 = 0.f;
        const int sbase = sh * 128;
#pragma unroll 8
        for (int s = 0; s < 128; ++s)
            acc2 = fmaf(ys[sbase + s], bf2f(zp[(long long)(sbase + s) * 2048]), acc2);
        red2[tid] = acc2; __syncthreads();
        if (sh == 0)
            out[(long long)b * 2048 + c] = (8.0f * ALPHA) * (red2[tid] + red2[tid + 128]);
    } else {
        float* red = (float*)smem;
        float s = 0.f;
        for (int i = tid; i < 16 * 512; i += 256) { const float v = wmean[i]; s += v * v; }
        red[tid] = s; __syncthreads();
        for (int st = 128; st > 0; st >>= 1) { if (tid < st) red[tid] += red[tid + st]; __syncthreads(); }
        if (tid == 0) {
            const float l = wlv[0];
            out[327681] = 0.5f * (red[0] + 8192.0f * (expf(l) - 1.0f - l));
        }
    }
}

// ---------------------------------------------------------------------------
// Z_r_kv partials: M=16 b, N=18432 d, K=2048, K-split 8 -> grid (288, 8).
// W loads NON-TEMPORAL. Store layout: 64B-contiguous runs per wave.
// ---------------------------------------------------------------------------
__global__ __launch_bounds__(256)
void zrkv_mfma_kernel(const float* __restrict__ W, const float* __restrict__ zr,
                      float* __restrict__ part)
{
    const int tid = threadIdx.x, lane = tid & 63, w = tid >> 6;
    const int bx = blockIdx.x, ky = blockIdx.y;
    const int d0 = bx * 64 + w * 16;
    const int kc0 = ky * 256;
    const int rr = lane & 15, kq = lane >> 4;
    s16x8 areg[8];
    const float* zb = zr + rr * 2048 + kc0 + kq * 8;
#pragma unroll
    for (int s = 0; s < 8; ++s) {
        const f32x4 a0 = *(const f32x4*)(zb + s * 32);
        const f32x4 a1 = *(const f32x4*)(zb + s * 32 + 4);
        u16x8 h;
#pragma unroll
        for (int j = 0; j < 4; ++j) { h[j] = f2bf(a0[j]); h[j + 4] = f2bf(a1[j]); }
        areg[s] = __builtin_bit_cast(s16x8, h);
    }
    f32x4 acc = {0.f, 0.f, 0.f, 0.f};
    const float* wb = W + (long long)(d0 + rr) * 2048 + kc0 + kq * 8;
#pragma unroll
    for (int s = 0; s < 8; ++s) {
        const f32x4 b0 = __builtin_nontemporal_load((const f32x4*)(wb + s * 32));
        const f32x4 b1 = __builtin_nontemporal_load((const f32x4*)(wb + s * 32 + 4));
        u16x8 h;
#pragma unroll
        for (int j = 0; j < 4; ++j) { h[j] = f2bf(b0[j]); h[j + 4] = f2bf(b1[j]); }
        acc = mfma16(areg[s], __builtin_bit_cast(s16x8, h), acc);
    }
    float* pb = part + (((long long)ky * 288 + bx) * 4 + w) * 256 + kq * 64 + rr;
#pragma unroll
    for (int r = 0; r < 4; ++r) pb[r * 16] = acc[r];
}

// out[b*18432+d] = sum_ky part[...]   grid (72, 16)
__global__ __launch_bounds__(256)
void zrkv_combine_kernel(const float* __restrict__ part, float* __restrict__ out)
{
    const int b = blockIdx.y;
    const int d = blockIdx.x * 256 + threadIdx.x;
    const int base = ((d >> 6) * 4 + ((d >> 4) & 3)) * 256 + b * 16 + (d & 15);
    float s = 0.f;
#pragma unroll
    for (int ky = 0; ky < 8; ++ky)
        s += part[(long long)ky * 294912 + base];
    out[(long long)b * 18432 + d] = s;
}

extern "C" void kernel_launch(void* const* d_in, const int* in_sizes, int n_in,
                              void* d_out, int out_size, void* d_ws, size_t ws_size,
                              hipStream_t stream)
{
    (void)in_sizes; (void)n_in; (void)out_size; (void)ws_size;
    const float* z_seq   = (const float*)d_in[0];
    const float* z_query = (const float*)d_in[1];
    const float* noise   = (const float*)d_in[2];
    const float* mm      = (const float*)d_in[3];
    const float* mlv     = (const float*)d_in[4];
    const float* wlv     = (const float*)d_in[5];
    const float* WM      = (const float*)d_in[6];
    float* out = (float*)d_out;   // [zr 32768 | Zrkv 294912 | dkl_M | dkl_w]

    char* wsb = (char*)d_ws;
    unsigned short* ztb  = (unsigned short*)(wsb);                  // 16 MB (B,S,C) bf16
    unsigned short* wTb  = (unsigned short*)(wsb + (16LL << 20));   // 4 MB (B,K,S) bf16
    float*          G1   = (float*)(wsb + (24LL << 20));            // 1 MB (K,K) f32
    unsigned short* P1b  = (unsigned short*)(wsb + (26LL << 20));   // 2 MB (C,K) bf16
    float*          pZ   = (float*)(wsb + (40LL << 20));            // 9.4 MB zrkv partials
    float*          vec  = (float*)(wsb + (52LL << 20));
    float* qvec     = vec;           // 4096
    float* wmean    = vec + 4096;    // 8192

    // 0. zero-init accumulation targets (graph-capturable memset nodes)
    hipMemsetAsync(G1, 0, 512 * 512 * sizeof(float), stream);
    hipMemsetAsync(wmean, 0, 8192 * sizeof(float), stream);
    hipMemsetAsync(out + 327680, 0, sizeof(float), stream);
    // 1. prep (zt + q)  ||  G1 = mm @ mm^T (K-split 8, atomicAdd, XCD-pinned)
    fused_prep_kernel<<<4608, 256, 0, stream>>>(z_seq, noise, z_query, mm,
                                                ztb, qvec, G1);
    // 2. P1 = 8a*mm^T - 28a^2*(mm^T @ G1) -> bf16  (2048,512,512)
    gemm_mfma<64,64,true,false,false,false,true,false,true><<<dim3(8,32,1),256,0,stream>>>(
        mm,2048,0, G1,512,0, P1b,512,0, mm,2048,
        -28.0f*ALPHA*ALPHA, 8.0f*ALPHA, 512);
    // 3. wT = (zt @ P1)^T bf16, + fused u -> wmean (atomics), XCD-pinned A reuse
    wT_u_kernel<<<256,256,0,stream>>>(ztb, P1b, wTb, qvec, wmean);
    // 4. nmm+dkl_M  ||  zret  ||  dkl_w  (XCD-pinned batch panels)
    tail_kernel<<<1281,256,0,stream>>>(wTb, ztb, mm, mlv, wmean, wlv, out);
    // 5-6. Z_r_kv = zr @ W^T (K-split 8 MFMA stream + combine)
    zrkv_mfma_kernel<<<dim3(288,8),256,0,stream>>>(WM, out, pZ);
    zrkv_combine_kernel<<<dim3(72,16),256,0,stream>>>(pZ, out + 32768);
}

// Round 11
// 177.615 us; speedup vs baseline: 1.5354x; 1.0215x over previous
//
#include <hip/hip_runtime.h>

#define ALPHA 5.0e-4f

typedef short s16x8 __attribute__((ext_vector_type(8)));
typedef unsigned short u16x8 __attribute__((ext_vector_type(8)));
typedef float f32x4 __attribute__((ext_vector_type(4)));

__device__ __forceinline__ unsigned short f2bf(float f) {
    unsigned int u = __builtin_bit_cast(unsigned int, f);
    u += 0x7fffu + ((u >> 16) & 1u);
    return (unsigned short)(u >> 16);
}
__device__ __forceinline__ float bf2f(unsigned short h) {
    return __builtin_bit_cast(float, (unsigned int)h << 16);
}
__device__ __forceinline__ f32x4 mfma16(s16x8 a, s16x8 b, f32x4 c) {
    return __builtin_amdgcn_mfma_f32_16x16x32_bf16(a, b, c, 0, 0, 0);
}

// ---------------------------------------------------------------------------
// Staging helpers -> LDS tile [ROWS][64 bf16], XOR-swizzled (slot ^= row&7).
// ---------------------------------------------------------------------------
template<int ROWS>
__device__ __forceinline__ void stage_kcontig(const float* __restrict__ src, int ld,
                                              unsigned short* __restrict__ lds, int tid)
{
#pragma unroll
    for (int it = 0; it < ROWS * 8 / 256; ++it) {
        const int g = tid + it * 256;
        const int row = g >> 3, s = g & 7;
        const float* p = src + (long long)row * ld + s * 8;
        const float4 x0 = *(const float4*)p;
        const float4 x1 = *(const float4*)(p + 4);
        u16x8 h;
        h[0] = f2bf(x0.x); h[1] = f2bf(x0.y); h[2] = f2bf(x0.z); h[3] = f2bf(x0.w);
        h[4] = f2bf(x1.x); h[5] = f2bf(x1.y); h[6] = f2bf(x1.z); h[7] = f2bf(x1.w);
        *(u16x8*)(lds + row * 64 + ((s ^ (row & 7)) << 3)) = h;
    }
}

template<int ROWS>
__device__ __forceinline__ void stage_kstrided(const float* __restrict__ src, int ld,
                                               unsigned short* __restrict__ lds, int tid)
{
    constexpr int KPT = ROWS * 64 / 256;
    const int m = tid % ROWS, kb = (tid / ROWS) * KPT;
#pragma unroll
    for (int j8 = 0; j8 < KPT / 8; ++j8) {
        u16x8 h;
#pragma unroll
        for (int j = 0; j < 8; ++j)
            h[j] = f2bf(src[(long long)(kb + j8 * 8 + j) * ld + m]);
        const int s = (kb >> 3) + j8;
        *(u16x8*)(lds + m * 64 + ((s ^ (m & 7)) << 3)) = h;
    }
}

template<int ROWS>
__device__ __forceinline__ void stage_kcontig_b(const unsigned short* __restrict__ src, int ld,
                                                unsigned short* __restrict__ lds, int tid)
{
#pragma unroll
    for (int it = 0; it < ROWS * 8 / 256; ++it) {
        const int g = tid + it * 256;
        const int row = g >> 3, s = g & 7;
        const u16x8 h = *(const u16x8*)(src + (long long)row * ld + s * 8);
        *(u16x8*)(lds + row * 64 + ((s ^ (row & 7)) << 3)) = h;
    }
}

template<int ROWS>
__device__ __forceinline__ void stage_kstrided_b(const unsigned short* __restrict__ src, int ld,
                                                 unsigned short* __restrict__ lds, int tid)
{
    constexpr int KPT = ROWS * 64 / 256;
    const int m = tid % ROWS, kb = (tid / ROWS) * KPT;
#pragma unroll
    for (int j8 = 0; j8 < KPT / 8; ++j8) {
        u16x8 h;
#pragma unroll
        for (int j = 0; j < 8; ++j)
            h[j] = src[(long long)(kb + j8 * 8 + j) * ld + m];
        const int s = (kb >> 3) + j8;
        *(u16x8*)(lds + m * 64 + ((s ^ (m & 7)) << 3)) = h;
    }
}

// ---------------------------------------------------------------------------
// GEMM device body:  D = alpha*op(A)@op(B) + beta*Cin   (ATOM: atomicAdd f32)
// ---------------------------------------------------------------------------
template<int BM, int BN, bool TA, bool TB, bool ABF, bool BBF, bool OBF,
         bool OT, bool CINT, bool ATOM = false>
__device__ __forceinline__
void gemm_dev(int bx, int by, int bz,
              const void* __restrict__ Av, int lda, long long sA,
              const void* __restrict__ Bv, int ldb, long long sB,
              void* __restrict__ Dv, int ldd, long long sD,
              const float* __restrict__ Cin, long long sC,
              float alpha, float beta, int Kd)
{
    constexpr int TWM = BM / 2, TWN = BN / 2;
    constexpr int FM = TWM / 16, FN = TWN / 16;
    __shared__ unsigned short As[BM * 64];
    __shared__ unsigned short Bs[BN * 64];

    const int tid = threadIdx.x;
    const int lane = tid & 63, w = tid >> 6;
    const int wm = w >> 1, wn = w & 1;
    const int lrow = lane & 15, lk = lane >> 4;
    const int m0 = by * BM, n0 = bx * BN;

    f32x4 acc[FM][FN];
#pragma unroll
    for (int i = 0; i < FM; ++i)
#pragma unroll
        for (int j = 0; j < FN; ++j) acc[i][j] = (f32x4){0.f, 0.f, 0.f, 0.f};

    for (int k0 = 0; k0 < Kd; k0 += 64) {
        if (ABF) {
            const unsigned short* Ab = (const unsigned short*)Av + (long long)bz * sA;
            if (!TA) stage_kcontig_b<BM>(Ab + (long long)m0 * lda + k0, lda, As, tid);
            else     stage_kstrided_b<BM>(Ab + (long long)k0 * lda + m0, lda, As, tid);
        } else {
            const float* Ab = (const float*)Av + (long long)bz * sA;
            if (!TA) stage_kcontig<BM>(Ab + (long long)m0 * lda + k0, lda, As, tid);
            else     stage_kstrided<BM>(Ab + (long long)k0 * lda + m0, lda, As, tid);
        }
        if (BBF) {
            const unsigned short* Bb = (const unsigned short*)Bv + (long long)bz * sB;
            if (TB)  stage_kcontig_b<BN>(Bb + (long long)n0 * ldb + k0, ldb, Bs, tid);
            else     stage_kstrided_b<BN>(Bb + (long long)k0 * ldb + n0, ldb, Bs, tid);
        } else {
            const float* Bb = (const float*)Bv + (long long)bz * sB;
            if (TB)  stage_kcontig<BN>(Bb + (long long)n0 * ldb + k0, ldb, Bs, tid);
            else     stage_kstrided<BN>(Bb + (long long)k0 * ldb + n0, ldb, Bs, tid);
        }
        __syncthreads();
#pragma unroll
        for (int kk = 0; kk < 2; ++kk) {
            s16x8 ah[FM], bh[FN];
#pragma unroll
            for (int i = 0; i < FM; ++i) {
                const int row = wm * TWM + i * 16 + lrow;
                const int s = kk * 4 + lk;
                ah[i] = *(const s16x8*)(As + row * 64 + ((s ^ (row & 7)) << 3));
            }
#pragma unroll
            for (int j = 0; j < FN; ++j) {
                const int col = wn * TWN + j * 16 + lrow;
                const int s = kk * 4 + lk;
                bh[j] = *(const s16x8*)(Bs + col * 64 + ((s ^ (col & 7)) << 3));
            }
#pragma unroll
            for (int i = 0; i < FM; ++i)
#pragma unroll
                for (int j = 0; j < FN; ++j)
                    acc[i][j] = mfma16(ah[i], bh[j], acc[i][j]);
        }
        __syncthreads();
    }

#pragma unroll
    for (int i = 0; i < FM; ++i)
#pragma unroll
        for (int j = 0; j < FN; ++j) {
            const int col = n0 + wn * TWN + j * 16 + lrow;
#pragma unroll
            for (int r = 0; r < 4; ++r) {
                const int row = m0 + wm * TWM + i * 16 + lk * 4 + r;
                float v = alpha * acc[i][j][r];
                if (Cin) {
                    const float cv = CINT ? Cin[(long long)col * sC + row]
                                          : Cin[(long long)row * ldd + col];
                    v = fmaf(beta, cv, v);
                }
                if (ATOM) {
                    atomicAdd((float*)Dv + (long long)row * ldd + col, v);
                } else if (OT) {
                    ((unsigned short*)Dv)[(long long)(row >> 8) * sD +
                                          (long long)col * ldd + (row & 255)] = f2bf(v);
                } else if (OBF) {
                    ((unsigned short*)Dv + (long long)bz * sD)[(long long)row * ldd + col] = f2bf(v);
                } else {
                    ((float*)Dv + (long long)bz * sD)[(long long)row * ldd + col] = v;
                }
            }
        }
}

template<int BM, int BN, bool TA, bool TB, bool ABF, bool BBF, bool OBF,
         bool OT = false, bool CINT = false>
__global__ __launch_bounds__(256)
void gemm_mfma(const void* __restrict__ Av, int lda, long long sA,
               const void* __restrict__ Bv, int ldb, long long sB,
               void* __restrict__ Dv, int ldd, long long sD,
               const float* __restrict__ Cin, long long sC,
               float alpha, float beta, int Kd)
{
    gemm_dev<BM, BN, TA, TB, ABF, BBF, OBF, OT, CINT>(
        blockIdx.x, blockIdx.y, blockIdx.z,
        Av, lda, sA, Bv, ldb, sB, Dv, ldd, sD, Cin, sC, alpha, beta, Kd);
}

// ---------------------------------------------------------------------------
// fused_prep: blocks 0..4095: zt/q prep; 4096..4607: G1 K-split-8 partial GEMM.
// ---------------------------------------------------------------------------
__global__ __launch_bounds__(256)
void fused_prep_kernel(const float* __restrict__ zs, const float* __restrict__ no,
                       const float* __restrict__ zq, const float* __restrict__ mm,
                       unsigned short* __restrict__ ztb, float* __restrict__ q,
                       float* __restrict__ G1)
{
    const int blk = blockIdx.x, t = threadIdx.x;
    if (blk < 4096) {
        const int bs = blk;                 // b*256 + s
        const int b = bs >> 8, sI = bs & 255;
        const long long in = ((long long)sI * 16 + b) * 2048 + t * 8;
        const f32x4 z0 = __builtin_nontemporal_load((const f32x4*)(zs + in));
        const f32x4 z1 = __builtin_nontemporal_load((const f32x4*)(zs + in + 4));
        const f32x4 n0 = __builtin_nontemporal_load((const f32x4*)(no + in));
        const f32x4 n1 = __builtin_nontemporal_load((const f32x4*)(no + in + 4));
        float zf[8];
#pragma unroll
        for (int j = 0; j < 4; ++j) {
            zf[j]     = fmaf(0.01f, n0[j], z0[j]);
            zf[j + 4] = fmaf(0.01f, n1[j], z1[j]);
        }
        u16x8 o;
#pragma unroll
        for (int j = 0; j < 8; ++j) o[j] = f2bf(zf[j]);
        *(u16x8*)(ztb + ((long long)bs * 2048 + t * 8)) = o;
        const float4 q0 = *(const float4*)(zq + b * 2048 + t * 8);
        const float4 q1 = *(const float4*)(zq + b * 2048 + t * 8 + 4);
        float qa = zf[0] * q0.x + zf[1] * q0.y + zf[2] * q0.z + zf[3] * q0.w
                 + zf[4] * q1.x + zf[5] * q1.y + zf[6] * q1.z + zf[7] * q1.w;
        __shared__ float red[256];
        red[t] = qa; __syncthreads();
        for (int st = 128; st > 0; st >>= 1) { if (t < st) red[t] += red[t + st]; __syncthreads(); }
        if (t == 0) q[bs] = red[0];
    } else {
        const int g = blk - 4096;           // 0..511
        const int ky = g & 7;               // K-chunk, XCD-pinned
        const int tile = g >> 3;            // 0..63
        gemm_dev<64, 64, false, true, false, false, false, false, false, true>(
            tile & 7, tile >> 3, 0,
            mm + ky * 256, 2048, 0, mm + ky * 256, 2048, 0,
            G1, 512, 0, nullptr, 0, 1.f, 0.f, 256);
    }
}

// ---------------------------------------------------------------------------
// wT GEMM (zt @ P1 -> bf16 transposed) + fused u: wmean += 64a^2 * w^T q.
// 1D grid 256, XCD-pinned A-panel reuse.
// ---------------------------------------------------------------------------
__global__ __launch_bounds__(256)
void wT_u_kernel(const unsigned short* __restrict__ ztb,
                 const unsigned short* __restrict__ P1b,
                 unsigned short* __restrict__ wTb,
                 const float* __restrict__ q, float* __restrict__ wmean)
{
    constexpr int BM = 128, BN = 64, TWM = 64, TWN = 32, FM = 4, FN = 2;
    __shared__ unsigned short As[BM * 64];
    __shared__ unsigned short Bs[BN * 64];
    const int lin = blockIdx.x;
    const int r = lin & 7, tt = lin >> 3;
    const int by = r + 8 * (tt & 3), bx = tt >> 2;
    const int tid = threadIdx.x;
    const int lane = tid & 63, w = tid >> 6;
    const int wm = w >> 1, wn = w & 1;
    const int lrow = lane & 15, lk = lane >> 4;
    const int m0 = by * BM, n0 = bx * BN;

    f32x4 acc[FM][FN];
#pragma unroll
    for (int i = 0; i < FM; ++i)
#pragma unroll
        for (int j = 0; j < FN; ++j) acc[i][j] = (f32x4){0.f, 0.f, 0.f, 0.f};

    for (int k0 = 0; k0 < 2048; k0 += 64) {
        stage_kcontig_b<BM>(ztb + (long long)m0 * 2048 + k0, 2048, As, tid);
        stage_kstrided_b<BN>(P1b + (long long)k0 * 512 + n0, 512, Bs, tid);
        __syncthreads();
#pragma unroll
        for (int kk = 0; kk < 2; ++kk) {
            s16x8 ah[FM], bh[FN];
#pragma unroll
            for (int i = 0; i < FM; ++i) {
                const int row = wm * TWM + i * 16 + lrow;
                const int s = kk * 4 + lk;
                ah[i] = *(const s16x8*)(As + row * 64 + ((s ^ (row & 7)) << 3));
            }
#pragma unroll
            for (int j = 0; j < FN; ++j) {
                const int col = wn * TWN + j * 16 + lrow;
                const int s = kk * 4 + lk;
                bh[j] = *(const s16x8*)(Bs + col * 64 + ((s ^ (col & 7)) << 3));
            }
#pragma unroll
            for (int i = 0; i < FM; ++i)
#pragma unroll
                for (int j = 0; j < FN; ++j)
                    acc[i][j] = mfma16(ah[i], bh[j], acc[i][j]);
        }
        __syncthreads();
    }

    float up[FN] = {0.f, 0.f};
#pragma unroll
    for (int i = 0; i < FM; ++i)
#pragma unroll
        for (int rr = 0; rr < 4; ++rr) {
            const int row = m0 + wm * TWM + i * 16 + lk * 4 + rr;
            const float qv = q[row];
#pragma unroll
            for (int j = 0; j < FN; ++j) {
                const int col = n0 + wn * TWN + j * 16 + lrow;
                const float v = acc[i][j][rr];
                wTb[(long long)(row >> 8) * 131072 + (long long)col * 256 + (row & 255)] = f2bf(v);
                up[j] = fmaf(v, qv, up[j]);
            }
        }
    const int b = m0 >> 8;
#pragma unroll
    for (int j = 0; j < FN; ++j) {
        float v = up[j];
        v += __shfl_xor(v, 16);
        v += __shfl_xor(v, 32);
        if (lk == 0) {
            const int col = n0 + wn * TWN + j * 16 + lrow;
            atomicAdd(&wmean[b * 512 + col], (64.0f * ALPHA * ALPHA) * v);
        }
    }
}

// ---------------------------------------------------------------------------
// tail1: blocks 0..255 zret (XCD-pinned by b); block 256 dkl_w.
// ---------------------------------------------------------------------------
__global__ __launch_bounds__(256)
void tail1_kernel(const unsigned short* __restrict__ wTb,
                  const unsigned short* __restrict__ ztb,
                  const float* __restrict__ wmean, const float* __restrict__ wlv,
                  float* __restrict__ out)
{
    __shared__ __align__(16) float smemf[1024];
    const int blk = blockIdx.x, tid = threadIdx.x;
    if (blk < 256) {
        float* wms = smemf;                  // 512
        float* ys  = smemf + 512;            // 256
        float* red2 = smemf + 768;           // 256
        const int r8 = blk & 7, t8 = blk >> 3;
        const int b = r8 + 8 * (t8 & 1), ct = t8 >> 1;   // b XCD-pinned
        wms[tid] = wmean[b * 512 + tid];
        wms[tid + 256] = wmean[b * 512 + 256 + tid];
        __syncthreads();
        {
            const unsigned short* wp = wTb + (long long)b * 131072 + tid;
            float yv = 0.f;
#pragma unroll 8
            for (int k = 0; k < 512; ++k)
                yv = fmaf(wms[k], bf2f(wp[(long long)k * 256]), yv);
            ys[tid] = yv;
        }
        __syncthreads();
        const int c = ct * 128 + (tid & 127), sh = tid >> 7;
        const unsigned short* zp = ztb + (long long)b * 524288 + c;
        float acc2 = 0.f;
        const int sbase = sh * 128;
#pragma unroll 8
        for (int s = 0; s < 128; ++s)
            acc2 = fmaf(ys[sbase + s], bf2f(zp[(long long)(sbase + s) * 2048]), acc2);
        red2[tid] = acc2; __syncthreads();
        if (sh == 0)
            out[(long long)b * 2048 + c] = (8.0f * ALPHA) * (red2[tid] + red2[tid + 128]);
    } else {
        float* red = smemf;
        float s = 0.f;
        for (int i = tid; i < 16 * 512; i += 256) { const float v = wmean[i]; s += v * v; }
        red[tid] = s; __syncthreads();
        for (int st = 128; st > 0; st >>= 1) { if (tid < st) red[tid] += red[tid + st]; __syncthreads(); }
        if (tid == 0) {
            const float l = wlv[0];
            out[327681] = 0.5f * (red[0] + 8192.0f * (expf(l) - 1.0f - l));
        }
    }
}

// ---------------------------------------------------------------------------
// tail2: interleaved co-launch of
//   nmm+dkl GEMM (1024 blocks, compute-bound, XCD-pinned bz) and
//   zrkv MFMA stream (2304 blocks, HBM-bound, NT loads, atomicAdd to out).
// Groups of 26 blocks: 8 nmm + 18 zrkv, so both run concurrently.
// nmm XCD pin: group base shifts by 26%8=2 per group, compensated in bz.
// ---------------------------------------------------------------------------
__global__ __launch_bounds__(256)
void tail2_kernel(const unsigned short* __restrict__ wTb,
                  const unsigned short* __restrict__ ztb,
                  const float* __restrict__ mm, const float* __restrict__ mlv,
                  const float* __restrict__ WM, float* __restrict__ out)
{
    __shared__ __align__(16) unsigned char smem[34304];
    const int g = blockIdx.x, tid = threadIdx.x;
    const int grp = g / 26, p = g % 26;
    if (p < 8) {
        // ---- nmm + dkl_M ----
        constexpr int BM = 128, BN = 128, TWM = 64, TWN = 64, FM = 4, FN = 4;
        unsigned short* As = (unsigned short*)smem;               // 16384 B
        unsigned short* Bs = As + BM * 64;                        // 16384 B
        float* ivars = (float*)(smem + 32768);                    // 512 B
        float* red = (float*)(smem + 33280);                      // 1024 B
        const int bz = ((2 * grp + p) & 7) + 8 * (grp & 1);       // XCD-pinned
        const int rest = grp >> 1;                                // 0..63
        const int by = rest & 3, bx = rest >> 2;
        const int lane = tid & 63, w = tid >> 6;
        const int wm = w >> 1, wn = w & 1;
        const int lrow = lane & 15, lk = lane >> 4;
        const int m0 = by * BM, n0 = bx * BN;

        if (tid < 128) ivars[tid] = 1.0f / (expf(mlv[m0 + tid]) + 1e-6f);

        f32x4 acc[FM][FN];
#pragma unroll
        for (int i = 0; i < FM; ++i)
#pragma unroll
            for (int j = 0; j < FN; ++j) acc[i][j] = (f32x4){0.f, 0.f, 0.f, 0.f};

        for (int k0 = 0; k0 < 256; k0 += 64) {
            stage_kcontig_b<BM>(wTb + (long long)bz * 131072 + (long long)m0 * 256 + k0, 256, As, tid);
            stage_kstrided_b<BN>(ztb + (long long)bz * 524288 + (long long)k0 * 2048 + n0, 2048, Bs, tid);
            __syncthreads();
#pragma unroll
            for (int kk = 0; kk < 2; ++kk) {
                s16x8 ah[FM], bh[FN];
#pragma unroll
                for (int i = 0; i < FM; ++i) {
                    const int row = wm * TWM + i * 16 + lrow;
                    const int s = kk * 4 + lk;
                    ah[i] = *(const s16x8*)(As + row * 64 + ((s ^ (row & 7)) << 3));
                }
#pragma unroll
                for (int j = 0; j < FN; ++j) {
                    const int col = wn * TWN + j * 16 + lrow;
                    const int s = kk * 4 + lk;
                    bh[j] = *(const s16x8*)(Bs + col * 64 + ((s ^ (col & 7)) << 3));
                }
#pragma unroll
                for (int i = 0; i < FM; ++i)
#pragma unroll
                    for (int j = 0; j < FN; ++j)
                        acc[i][j] = mfma16(ah[i], bh[j], acc[i][j]);
            }
            __syncthreads();
        }

        const float A8 = 8.0f * ALPHA;
        float da = 0.f;
#pragma unroll
        for (int i = 0; i < FM; ++i)
#pragma unroll
            for (int j = 0; j < FN; ++j) {
                const int cl = wn * TWN + j * 16 + lrow;
#pragma unroll
                for (int rr = 0; rr < 4; ++rr) {
                    const int rl = wm * TWM + i * 16 + lk * 4 + rr;
                    const float v = A8 * acc[i][j][rr];
                    const float d = v - mm[(long long)(m0 + rl) * 2048 + (n0 + cl)];
                    da = fmaf(d * d, ivars[rl], da);
                }
            }
        red[tid] = da; __syncthreads();
        for (int st = 128; st > 0; st >>= 1) { if (tid < st) red[tid] += red[tid + st]; __syncthreads(); }
        if (tid == 0) atomicAdd(&out[327680], red[0] * (1.0f / 16.0f));
    } else {
        // ---- zrkv: Z_r_kv += zr @ W^T (K-chunk ky), NT W loads ----
        const int z = grp * 18 + (p - 8);        // 0..2303
        const int bx = z % 288, ky = z / 288;
        const int lane = tid & 63, w = tid >> 6;
        const int d0 = bx * 64 + w * 16;
        const int kc0 = ky * 256;
        const int rr = lane & 15, kq = lane >> 4;
        const float* zr = out;                   // out[0..32768) = z_retrieved
        s16x8 areg[8];
        const float* zb = zr + rr * 2048 + kc0 + kq * 8;
#pragma unroll
        for (int s = 0; s < 8; ++s) {
            const f32x4 a0 = *(const f32x4*)(zb + s * 32);
            const f32x4 a1 = *(const f32x4*)(zb + s * 32 + 4);
            u16x8 h;
#pragma unroll
            for (int j = 0; j < 4; ++j) { h[j] = f2bf(a0[j]); h[j + 4] = f2bf(a1[j]); }
            areg[s] = __builtin_bit_cast(s16x8, h);
        }
        f32x4 acc = {0.f, 0.f, 0.f, 0.f};
        const float* wb = WM + (long long)(d0 + rr) * 2048 + kc0 + kq * 8;
#pragma unroll
        for (int s = 0; s < 8; ++s) {
            const f32x4 b0 = __builtin_nontemporal_load((const f32x4*)(wb + s * 32));
            const f32x4 b1 = __builtin_nontemporal_load((const f32x4*)(wb + s * 32 + 4));
            u16x8 h;
#pragma unroll
            for (int j = 0; j < 4; ++j) { h[j] = f2bf(b0[j]); h[j + 4] = f2bf(b1[j]); }
            acc = mfma16(areg[s], __builtin_bit_cast(s16x8, h), acc);
        }
        float* oz = out + 32768;
#pragma unroll
        for (int r = 0; r < 4; ++r)
            atomicAdd(&oz[(long long)(kq * 4 + r) * 18432 + d0 + rr], acc[r]);
    }
}

extern "C" void kernel_launch(void* const* d_in, const int* in_sizes, int n_in,
                              void* d_out, int out_size, void* d_ws, size_t ws_size,
                              hipStream_t stream)
{
    (void)in_sizes; (void)n_in; (void)out_size; (void)ws_size;
    const float* z_seq   = (const float*)d_in[0];
    const float* z_query = (const float*)d_in[1];
    const float* noise   = (const float*)d_in[2];
    const float* mm      = (const float*)d_in[3];
    const float* mlv     = (const float*)d_in[4];
    const float* wlv     = (const float*)d_in[5];
    const float* WM      = (const float*)d_in[6];
    float* out = (float*)d_out;   // [zr 32768 | Zrkv 294912 | dkl_M | dkl_w]

    char* wsb = (char*)d_ws;
    unsigned short* ztb  = (unsigned short*)(wsb);                  // 16 MB (B,S,C) bf16
    unsigned short* wTb  = (unsigned short*)(wsb + (16LL << 20));   // 4 MB (B,K,S) bf16
    float*          G1   = (float*)(wsb + (24LL << 20));            // 1 MB (K,K) f32
    float*          wmean = (float*)(wsb + (25LL << 20));           // 32 KB (adjacent to G1)
    unsigned short* P1b  = (unsigned short*)(wsb + (26LL << 20));   // 2 MB (C,K) bf16
    float*          qvec = (float*)(wsb + (30LL << 20));            // 16 KB

    // 0. zero-init accumulation targets (G1+wmean contiguous; Zrkv+dkl_M in out)
    hipMemsetAsync(G1, 0, (1u << 20) + 32768, stream);
    hipMemsetAsync(out + 32768, 0, (294912 + 1) * sizeof(float), stream);
    // 1. prep (zt + q)  ||  G1 = mm @ mm^T (K-split 8, atomicAdd, XCD-pinned)
    fused_prep_kernel<<<4608, 256, 0, stream>>>(z_seq, noise, z_query, mm,
                                                ztb, qvec, G1);
    // 2. P1 = 8a*mm^T - 28a^2*(mm^T @ G1) -> bf16  (2048,512,512)
    gemm_mfma<64,64,true,false,false,false,true,false,true><<<dim3(8,32,1),256,0,stream>>>(
        mm,2048,0, G1,512,0, P1b,512,0, mm,2048,
        -28.0f*ALPHA*ALPHA, 8.0f*ALPHA, 512);
    // 3. wT = (zt @ P1)^T bf16, + fused u -> wmean (atomics), XCD-pinned A reuse
    wT_u_kernel<<<256,256,0,stream>>>(ztb, P1b, wTb, qvec, wmean);
    // 4. zret + dkl_w (needs wmean)
    tail1_kernel<<<257,256,0,stream>>>(wTb, ztb, wmean, wlv, out);
    // 5. co-launched nmm+dkl_M (compute)  ||  zrkv stream (HBM), interleaved 8:18
    tail2_kernel<<<3328,256,0,stream>>>(wTb, ztb, mm, mlv, WM, out);
}